// Round 5
// baseline (293832.788 us; speedup 1.0000x reference)
//
#include <hip/hip_runtime.h>
#include <math.h>

#define NB 128
#define KPH 3
#define MAXPER 48
#define MAXTOK 144
#define LATENT 128
#define HD 512
#define NMEM 8
#define NH 8
#define VOC 8000
#define CT 145
#define NBLK 512
#define SCALE 0.125f

// ---- device-coherent (agent-scope, sc1: bypass XCD L2, hit MALL) access ----
__device__ __forceinline__ float ldsc(const float* p) {
  return __hip_atomic_load(const_cast<float*>(p), __ATOMIC_RELAXED, __HIP_MEMORY_SCOPE_AGENT);
}
__device__ __forceinline__ void stsc(float* p, float v) {
  __hip_atomic_store(p, v, __ATOMIC_RELAXED, __HIP_MEMORY_SCOPE_AGENT);
}
__device__ __forceinline__ int ldsci(const int* p) {
  return __hip_atomic_load(const_cast<int*>(p), __ATOMIC_RELAXED, __HIP_MEMORY_SCOPE_AGENT);
}
__device__ __forceinline__ void stsci(int* p, int v) {
  __hip_atomic_store(p, v, __ATOMIC_RELAXED, __HIP_MEMORY_SCOPE_AGENT);
}

// ======================= setup kernels (run once) ==========================

__global__ void k_zero(float* __restrict__ p, int n) {
  int i = blockIdx.x * blockDim.x + threadIdx.x;
  if (i < n) p[i] = 0.0f;
}

__global__ void k_wz(const float* __restrict__ z_seq, const float* __restrict__ zw,
                     float* __restrict__ out) {
  int i = blockIdx.x * blockDim.x + threadIdx.x;
  if (i < NB * KPH * LATENT) out[i] = zw[i >> 7] * z_seq[i];
}

__global__ void k_copy(const float* __restrict__ src, float* __restrict__ dst, int n) {
  int i = blockIdx.x * blockDim.x + threadIdx.x;
  if (i < n) dst[i] = src[i];
}

__global__ __launch_bounds__(256) void k_gemm(
    const float* __restrict__ A, int lda,
    const float* __restrict__ W, int ldw, int K,
    float* __restrict__ out, int ostride)
{
  __shared__ float As[32][36];
  __shared__ float Ws[32][64];
  const int t = threadIdx.x;
  const int c0 = blockIdx.x * 64, b0 = blockIdx.y * 32;
  const int c = t & 63, g = t >> 6;
  float acc[8] = {0,0,0,0,0,0,0,0};
  const int ra = t >> 3, ka = (t & 7) << 2;
  for (int k0 = 0; k0 < K; k0 += 32) {
    const float4 a4 = *reinterpret_cast<const float4*>(A + (size_t)(b0 + ra) * lda + k0 + ka);
    As[ra][ka] = a4.x; As[ra][ka+1] = a4.y; As[ra][ka+2] = a4.z; As[ra][ka+3] = a4.w;
    #pragma unroll
    for (int e = 0; e < 8; e++) {
      int li = t + e * 256;
      Ws[li >> 6][li & 63] = W[(size_t)(k0 + (li >> 6)) * ldw + c0 + (li & 63)];
    }
    __syncthreads();
    #pragma unroll
    for (int kk = 0; kk < 32; kk++) {
      float wv = Ws[kk][c];
      #pragma unroll
      for (int i = 0; i < 8; i++) acc[i] += As[g*8+i][kk] * wv;
    }
    __syncthreads();
  }
  #pragma unroll
  for (int i = 0; i < 8; i++)
    out[(size_t)(b0 + g * 8 + i) * ostride + c0 + c] = acc[i];
}

__global__ void k_init(const float* __restrict__ zw, const float* __restrict__ temb,
                       float* __restrict__ XS, float* __restrict__ gf, int* __restrict__ iph,
                       int* __restrict__ cur, int* __restrict__ tip, int* __restrict__ pos,
                       int* __restrict__ done, int* __restrict__ act)
{
  int b = blockIdx.x;
  if (threadIdx.x == 0) {
    int a0 = zw[b*3+0] > 0.01f;
    act[b*3+0] = a0;
    act[b*3+1] = zw[b*3+1] > 0.01f;
    act[b*3+2] = zw[b*3+2] > 0.01f;
    cur[b] = 0; tip[b] = 0; pos[b] = 0; done[b] = !a0;
    gf[b] = a0 ? 1.0f : 0.0f; iph[b] = 0;
  }
  for (int c = threadIdx.x; c < HD; c += blockDim.x)
    XS[(size_t)b * 1024 + c] = temb[1 * HD + c];   // BOS = 1
}

// ======================= persistent decode =================================

struct DecP {
  const float *temb, *Wq, *Wk, *Wv, *Wo, *Wco, *W1, *W2, *Wout;
  const float *MCK, *MCV, *WCAT;
  float *KC, *VC, *XS, *X2, *X3, *X, *Qb, *CQ, *CA, *H1, *PV, *GF;
  int *PI, *CUR, *TIP, *POS, *DONE, *IPH, *ACT;
  float *TOK, *GEN, *BND, *HID;
  unsigned *bar;
};

// barrier v2: 64 spread arrival counters (8 blocks each); block 0 wave-0
// detects (one counter per lane), broadcasts 8 replicated go lines; others
// poll a single go line with backoff. All ops relaxed agent-scope (MALL).
__device__ __forceinline__ void gsync(unsigned* bar, unsigned epoch) {
  const int t = threadIdx.x, blk = blockIdx.x;
  __syncthreads();
  if (t == 0)
    __hip_atomic_fetch_add(&bar[(blk & 63) * 32], 1u,
                           __ATOMIC_RELAXED, __HIP_MEMORY_SCOPE_AGENT);
  if (blk == 0) {
    if (t < 64) {
      const unsigned tg = epoch * (NBLK / 64);
      int spin = 0;
      while (__hip_atomic_load(&bar[t * 32], __ATOMIC_RELAXED, __HIP_MEMORY_SCOPE_AGENT) < tg) {
        if (++spin > 2) __builtin_amdgcn_s_sleep(2);
      }
      if (t < 8)
        __hip_atomic_store(&bar[2048 + t * 32], epoch,
                           __ATOMIC_RELAXED, __HIP_MEMORY_SCOPE_AGENT);
    }
  } else if (t == 0) {
    int spin = 0;
    while (__hip_atomic_load(&bar[2048 + (blk & 7) * 32],
                             __ATOMIC_RELAXED, __HIP_MEMORY_SCOPE_AGENT) < epoch) {
      if (++spin > 2) __builtin_amdgcn_s_sleep(16);
    }
  }
  __syncthreads();
}

__global__ __launch_bounds__(256, 2) void k_decode(DecP p) {
  // LDS: AT ring (4 x 1024 floats max) + scratch (2112 floats, unioned per phase)
  __shared__ float smem[4096 + 2112];
  __shared__ int s_nxt;
  float* const scr = smem + 4096;

  const int t = threadIdx.x;
  const int blk = blockIdx.x;
  unsigned ep = 0;

  // ---- K-parallel pipelined GEMM: 8 rows x 64 cols, K mult of 32 (>=512).
  // Wave g accumulates k-residues {4j+g}; W stays in registers (never LDS);
  // A slab goes LDS-transposed, read as wave-uniform b128 broadcasts.
  // 4-deep pipeline, constant ring indices (fully unrolled x4).
  auto gemmk = [&](int bx, int by, const float* A, int lda,
                   const float* W, int ldw, int K,
                   const float* R, int rs,
                   float* out, int os, int oo, int dogelu) {
    const int c = t & 63, g = t >> 6;
    const int c0 = bx * 64, b0 = by * 8;
    const int ar = t >> 5, ac = t & 31;
    const int nslab = K >> 5;                 // multiple of 4
    float wreg[4][8], areg[4];
    float acc[8] = {0,0,0,0,0,0,0,0};
    float res0 = 0.f, res1 = 0.f;
    if (R) {
      res0 = ldsc(R + (size_t)(b0 + g * 2 + 0) * rs + c0 + c);
      res1 = ldsc(R + (size_t)(b0 + g * 2 + 1) * rs + c0 + c);
    }
    const float* Wb = W + c0 + c;
    const float* Ab = A + (size_t)(b0 + ar) * lda + ac;
    #pragma unroll
    for (int q = 0; q < 4; q++) {
      #pragma unroll
      for (int e = 0; e < 8; e++)
        wreg[q][e] = Wb[(size_t)(q * 32 + e * 4 + g) * ldw];
      areg[q] = ldsc(Ab + q * 32);
    }
    #define GSTEP(jb, q) {                                                     \
      const int j = (jb) + (q);                                                \
      float* AT = smem + (q) * 256;                                            \
      AT[ac * 8 + ar] = areg[q];                                               \
      __syncthreads();                                                         \
      _Pragma("unroll")                                                        \
      for (int e = 0; e < 8; e++) {                                            \
        const float* at = AT + (e * 4 + g) * 8;                                \
        float4 a0 = *reinterpret_cast<const float4*>(at);                      \
        float4 a1 = *reinterpret_cast<const float4*>(at + 4);                  \
        float wv = wreg[q][e];                                                 \
        acc[0] += a0.x * wv; acc[1] += a0.y * wv;                              \
        acc[2] += a0.z * wv; acc[3] += a0.w * wv;                              \
        acc[4] += a1.x * wv; acc[5] += a1.y * wv;                              \
        acc[6] += a1.z * wv; acc[7] += a1.w * wv;                              \
      }                                                                        \
      if (j + 4 < nslab) {                                                     \
        _Pragma("unroll")                                                      \
        for (int e = 0; e < 8; e++)                                            \
          wreg[q][e] = Wb[(size_t)((j + 4) * 32 + e * 4 + g) * ldw];           \
        areg[q] = ldsc(Ab + (j + 4) * 32);                                     \
      } }
    for (int jb = 0; jb < nslab; jb += 4) {
      GSTEP(jb, 0) GSTEP(jb, 1) GSTEP(jb, 2) GSTEP(jb, 3)
    }
    #undef GSTEP
    // cross-wave reduce (fixed order g=0..3) + epilogue
    __syncthreads();
    #pragma unroll
    for (int r = 0; r < 8; r++) scr[g * 512 + r * 64 + c] = acc[r];
    __syncthreads();
    #pragma unroll
    for (int i = 0; i < 2; i++) {
      int r = g * 2 + i;
      float v = scr[r * 64 + c] + scr[512 + r * 64 + c]
              + scr[1024 + r * 64 + c] + scr[1536 + r * 64 + c];
      v += (i == 0) ? res0 : res1;
      if (dogelu) {
        float x3 = v * v * v;
        v = 0.5f * v * (1.0f + tanhf(0.7978845608028654f * (v + 0.044715f * x3)));
      }
      stsc(out + (size_t)(b0 + r) * os + oo + c0 + c, v);
    }
  };

  // ---- logits tile: 32 rows x 64 cols, K=512, same pipeline + argmax ----
  auto logits_tile = [&](int bx, int by) {
    const int c = t & 63, g = t >> 6;
    const int c0 = bx * 64, b0 = by * 32;
    const int ra = t >> 3, ka = (t & 7) << 2;
    float wreg[4][8], areg[4][4];
    float acc[32];
    #pragma unroll
    for (int i = 0; i < 32; i++) acc[i] = 0.f;
    const float* Wb = p.Wout + c0 + c;
    const float* Ab = p.X + (size_t)(b0 + ra) * 512 + ka;
    #pragma unroll
    for (int q = 0; q < 4; q++) {
      #pragma unroll
      for (int e = 0; e < 8; e++)
        wreg[q][e] = Wb[(size_t)(q * 32 + e * 4 + g) * VOC];
      #pragma unroll
      for (int u = 0; u < 4; u++)
        areg[q][u] = ldsc(Ab + q * 32 + u);
    }
    #define LSTEP(jb, q) {                                                     \
      const int j = (jb) + (q);                                                \
      float* AT = smem + (q) * 1024;                                           \
      _Pragma("unroll")                                                        \
      for (int u = 0; u < 4; u++) AT[(ka + u) * 32 + ra] = areg[q][u];         \
      __syncthreads();                                                         \
      _Pragma("unroll")                                                        \
      for (int e = 0; e < 8; e++) {                                            \
        const float* at = AT + (e * 4 + g) * 32;                               \
        float wv = wreg[q][e];                                                 \
        _Pragma("unroll")                                                      \
        for (int qq = 0; qq < 8; qq++) {                                       \
          float4 av = *reinterpret_cast<const float4*>(at + qq * 4);           \
          acc[qq*4+0] += av.x * wv; acc[qq*4+1] += av.y * wv;                  \
          acc[qq*4+2] += av.z * wv; acc[qq*4+3] += av.w * wv;                  \
        }                                                                      \
      }                                                                        \
      if (j + 4 < 16) {                                                        \
        _Pragma("unroll")                                                      \
        for (int e = 0; e < 8; e++)                                            \
          wreg[q][e] = Wb[(size_t)((j + 4) * 32 + e * 4 + g) * VOC];           \
        _Pragma("unroll")                                                      \
        for (int u = 0; u < 4; u++)                                            \
          areg[q][u] = ldsc(Ab + (j + 4) * 32 + u);                            \
      } }
    for (int jb = 0; jb < 16; jb += 4) {
      LSTEP(jb, 0) LSTEP(jb, 1) LSTEP(jb, 2) LSTEP(jb, 3)
    }
    #undef LSTEP
    // serialized cross-wave accumulate into scr[32][65] (fixed order)
    __syncthreads();
    for (int w = 0; w < 4; w++) {
      if (g == w) {
        #pragma unroll
        for (int r = 0; r < 32; r++) {
          float* pr = &scr[r * 65 + c];
          *pr = (w == 0) ? acc[r] : (*pr + acc[r]);
        }
      }
      __syncthreads();
    }
    if (t < 32) {
      float best = scr[t * 65]; int bi = 0;
      for (int cc = 1; cc < 64; cc++) {        // serial -> first-index tie-break
        float v = scr[t * 65 + cc];
        if (v > best) { best = v; bi = cc; }
      }
      stsc(&p.PV[(size_t)(b0 + t) * 125 + bx], best);
      stsci(&p.PI[(size_t)(b0 + t) * 125 + bx], c0 + bi);
    }
  };

  for (int s = 0; s < MAXTOK; s++) {
    // ---- A: Q,K,V projections (slot s); KC/VC write-once, readers cache ----
    if (blk < 128)
      gemmk(blk & 7, blk >> 3, p.XS, 1024, p.Wq, 512, 512, nullptr, 0, p.Qb, 512, 0, 0);
    else if (blk < 256)
      gemmk((blk-128) & 7, (blk-128) >> 3, p.XS, 1024, p.Wk, 512, 512, nullptr, 0, p.KC, CT*512, s*512, 0);
    else if (blk < 384)
      gemmk((blk-256) & 7, (blk-256) >> 3, p.XS, 1024, p.Wv, 512, 512, nullptr, 0, p.VC, CT*512, s*512, 0);
    gsync(p.bar, ++ep);

    // ---- B: self-attention, T = s+1, one wave per (b,h) ----
    if (blk < 256) {
      const int T = s + 1;
      int lane = t & 63, w = t >> 6;
      int task = blk * 4 + w, b = task >> 3, h = task & 7;
      float* ql = scr + w * 224;
      float* sc = ql + 64;
      ql[lane] = ldsc(&p.Qb[(size_t)b * 512 + h * 64 + lane]);
      __syncthreads();
      float lmax = -INFINITY;
      for (int s0 = lane; s0 < T; s0 += 64) {
        const float4* kp = reinterpret_cast<const float4*>(p.KC + ((size_t)b * CT + s0) * 512 + h * 64);
        float d = 0.0f;
        #pragma unroll
        for (int e = 0; e < 16; e++) {
          float4 k4 = kp[e];
          d += ql[4*e]*k4.x + ql[4*e+1]*k4.y + ql[4*e+2]*k4.z + ql[4*e+3]*k4.w;
        }
        d *= SCALE;
        sc[s0] = d;
        lmax = fmaxf(lmax, d);
      }
      #pragma unroll
      for (int off = 32; off; off >>= 1) lmax = fmaxf(lmax, __shfl_xor(lmax, off, 64));
      float lsum = 0.0f;
      for (int s0 = lane; s0 < T; s0 += 64) {
        float e = expf(sc[s0] - lmax);
        sc[s0] = e; lsum += e;
      }
      #pragma unroll
      for (int off = 32; off; off >>= 1) lsum += __shfl_xor(lsum, off, 64);
      __syncthreads();
      float inv = 1.0f / lsum;
      float acc = 0.0f;
      const float* vb = p.VC + (size_t)b * CT * 512 + h * 64 + lane;
      for (int s0 = 0; s0 < T; s0++) acc += sc[s0] * vb[(size_t)s0 * 512];
      stsc(&p.XS[(size_t)b * 1024 + 512 + h * 64 + lane], acc * inv);
    }
    gsync(p.bar, ++ep);

    // ---- C: X2 = XIN + SA@Wo ; CQ = [XIN|SA]@WCAT (K=1024 fused) ----
    if (blk < 128)
      gemmk(blk & 7, blk >> 3, p.XS + 512, 1024, p.Wo, 512, 512, p.XS, 1024, p.X2, 512, 0, 0);
    else if (blk < 256)
      gemmk((blk-128) & 7, (blk-128) >> 3, p.XS, 1024, p.WCAT, 512, 1024, nullptr, 0, p.CQ, 512, 0, 0);
    gsync(p.bar, ++ep);

    // ---- D: cross-attention, one block per b ----
    if (blk < NB) {
      int b = blk;
      float* cqs = scr;           // 512
      float* scs = scr + 512;     // 64
      cqs[t]       = ldsc(&p.CQ[(size_t)b * 512 + t]);
      cqs[t + 256] = ldsc(&p.CQ[(size_t)b * 512 + t + 256]);
      __syncthreads();
      float gate = ldsc(&p.GF[b]);
      int ip = ldsci(&p.IPH[b]);
      const float* mk = p.MCK + (size_t)(b * KPH + ip) * NMEM * 512;
      if (t < 64) {
        int h = t >> 3, m = t & 7;
        const float4* kp = reinterpret_cast<const float4*>(mk + m * 512 + h * 64);
        float d = 0.0f;
        #pragma unroll
        for (int e = 0; e < 16; e++) {
          float4 k4 = kp[e];
          d += cqs[h*64+4*e]*k4.x + cqs[h*64+4*e+1]*k4.y + cqs[h*64+4*e+2]*k4.z + cqs[h*64+4*e+3]*k4.w;
        }
        scs[t] = d * SCALE * gate;
      }
      __syncthreads();
      const float* mv = p.MCV + (size_t)(b * KPH + ip) * NMEM * 512;
      #pragma unroll
      for (int half = 0; half < 2; half++) {
        int c = t + half * 256;
        int h = c >> 6;
        float mx = scs[h*8];
        #pragma unroll
        for (int m = 1; m < 8; m++) mx = fmaxf(mx, scs[h*8+m]);
        float ee[8]; float sum = 0.0f;
        #pragma unroll
        for (int m = 0; m < 8; m++) { ee[m] = expf(scs[h*8+m] - mx); sum += ee[m]; }
        float a = 0.0f;
        #pragma unroll
        for (int m = 0; m < 8; m++) a += ee[m] * mv[(size_t)m * 512 + c];
        stsc(&p.CA[(size_t)b * 512 + c], gate * a / sum);
      }
    }
    gsync(p.bar, ++ep);

    // ---- E: X3 = X2 + CA@Wco ----
    if (blk < 128)
      gemmk(blk & 7, blk >> 3, p.CA, 512, p.Wco, 512, 512, p.X2, 512, p.X3, 512, 0, 0);
    gsync(p.bar, ++ep);

    // ---- F: H1 = gelu(X3@W1), N=2048, all 512 blocks ----
    gemmk(blk & 31, blk >> 5, p.X3, 512, p.W1, 2048, 512, nullptr, 0, p.H1, 2048, 0, 1);
    gsync(p.bar, ++ep);

    // ---- G: X = X3 + H1@W2, K=2048 ----
    if (blk < 128)
      gemmk(blk & 7, blk >> 3, p.H1, 2048, p.W2, 512, 2048, p.X3, 512, p.X, 512, 0, 0);
    gsync(p.bar, ++ep);

    // ---- H: logits + argmax partials, 500 tiles ----
    if (blk < 500) logits_tile(blk % 125, blk / 125);
    gsync(p.bar, ++ep);

    // ---- I: argmax finish + state machine + hiddens + next embedding ----
    if (blk < NB) {
      int b = blk;
      float* sv = scr;
      int*   si = (int*)(scr + 256);
      float v = -INFINITY; int idx = 0x7fffffff;
      if (t < 125) { v = ldsc(&p.PV[(size_t)b * 125 + t]); idx = ldsci(&p.PI[(size_t)b * 125 + t]); }
      sv[t] = v; si[t] = idx;
      __syncthreads();
      for (int s2 = 128; s2 > 0; s2 >>= 1) {
        if (t < s2) {
          float v2 = sv[t + s2]; int i2 = si[t + s2];
          if (v2 > sv[t] || (v2 == sv[t] && i2 < si[t])) { sv[t] = v2; si[t] = i2; }
        }
        __syncthreads();
      }
      if (t == 0) {
        int nxt = si[0]; s_nxt = nxt;
        int dn = p.DONE[b]; int live = !dn;
        int pp = p.POS[b], tp = p.TIP[b], cp = p.CUR[b];
        if (pp < MAXTOK) {
          p.TOK[(size_t)b * MAXTOK + pp] = live ? (float)nxt : 0.0f;
          p.GEN[(size_t)b * MAXTOK + pp] = live ? 1.0f : 0.0f;
        }
        pp += live; tp += live;
        int eos = (nxt == 2) && (tp >= 1);
        int sw = (eos || (tp >= MAXPER)) && live;
        cp += sw;
        if (sw) tp = 0;
        int cpc = cp < 2 ? cp : 2;
        if (sw && (cp < KPH)) p.BND[(size_t)b * KPH + cpc] = (float)pp;
        dn = dn || (cp >= KPH) || (sw && !p.ACT[b*3 + cpc]);
        p.CUR[b] = cp; p.TIP[b] = tp; p.POS[b] = pp; p.DONE[b] = dn;
        stsc(&p.GF[b], (p.ACT[b*3 + cpc] && !dn) ? 1.0f : 0.0f);
        stsci(&p.IPH[b], cpc);
      }
      __syncthreads();
      int nxt = s_nxt;
      #pragma unroll
      for (int rep = 0; rep < 2; rep++) {
        int c = t + rep * 256;
        stsc(&p.XS[(size_t)b * 1024 + c], p.temb[(size_t)nxt * 512 + c]);
        p.HID[((size_t)s * NB + b) * 512 + c] = ldsc(&p.X[(size_t)b * 512 + c]);
      }
    }
    gsync(p.bar, ++ep);
  }
}

// ======================= host ==============================================

extern "C" void kernel_launch(void* const* d_in, const int* in_sizes, int n_in,
                              void* d_out, int out_size, void* d_ws, size_t ws_size,
                              hipStream_t stream)
{
  const float* z_seq = (const float*)d_in[0];
  const float* z_w   = (const float*)d_in[1];
  const float* W_l2d = (const float*)d_in[2];
  const float* temb  = (const float*)d_in[3];
  const float* Wq  = (const float*)d_in[4];
  const float* Wk  = (const float*)d_in[5];
  const float* Wv  = (const float*)d_in[6];
  const float* Wo  = (const float*)d_in[7];
  const float* Wcq = (const float*)d_in[8];
  const float* Wck = (const float*)d_in[9];
  const float* Wcv = (const float*)d_in[10];
  const float* Wco = (const float*)d_in[11];
  const float* W1  = (const float*)d_in[12];
  const float* W2  = (const float*)d_in[13];
  const float* Wout= (const float*)d_in[14];

  float* fw = (float*)d_ws;
  size_t o = 4096;   // first 4096 words: barrier counters + go lines
  auto alloc = [&](size_t n) { float* r = fw + o; o += (n + 63) & ~(size_t)63; return r; };
  float* MCK = alloc((size_t)NB*KPH*NMEM*HD);
  float* MCV = alloc((size_t)NB*KPH*NMEM*HD);
  float* MEM = alloc((size_t)NB*KPH*NMEM*HD);   // reused as WCAT after setup
  float* KC  = alloc((size_t)NB*CT*HD);
  float* VC  = alloc((size_t)NB*CT*HD);
  float* XS  = alloc((size_t)NB*1024);          // [XIN | SA]
  float* X2  = alloc((size_t)NB*HD);
  float* X3  = alloc((size_t)NB*HD);
  float* X   = alloc((size_t)NB*HD);
  float* Qb  = alloc((size_t)NB*HD);
  float* CQ  = alloc((size_t)NB*HD);
  float* CA  = alloc((size_t)NB*HD);
  float* H1  = alloc((size_t)NB*4*HD);
  float* WZ  = alloc((size_t)NB*KPH*LATENT);
  float* PV  = alloc((size_t)NB*125);
  float* GF  = alloc(NB);
  int* ib = (int*)alloc(0);
  size_t io = 0;
  auto ialloc = [&](size_t n) { int* r = ib + io; io += (n + 63) & ~(size_t)63; return r; };
  int* PI  = ialloc((size_t)NB*125);
  int* CUR = ialloc(NB);
  int* TIP = ialloc(NB);
  int* POS = ialloc(NB);
  int* DONE= ialloc(NB);
  int* IPH = ialloc(NB);
  int* ACT = ialloc(NB*KPH);

  float* WCAT = MEM;   // [Wcq ; Wo@Wcq]  (1024 x 512) — overlays MEM after setup

  float* out_f = (float*)d_out;
  float* TOK  = out_f;
  float* GEN  = out_f + NB*MAXTOK;
  float* BND  = out_f + 2*NB*MAXTOK;
  float* HID  = out_f + 2*NB*MAXTOK + NB*KPH;

  // ---- one-time setup (plain kernels; dispatch boundaries give coherence) ----
  k_zero<<<16, 256, 0, stream>>>(fw, 4096);                               // barrier
  int nz = 2*NB*MAXTOK + NB*KPH;
  k_zero<<<(nz + 255)/256, 256, 0, stream>>>(out_f, nz);                  // tok/gen/bnd
  k_wz<<<(NB*KPH*LATENT + 255)/256, 256, 0, stream>>>(z_seq, z_w, WZ);
  k_gemm<<<dim3(64,12),256,0,stream>>>(WZ, 128, W_l2d, 4096, 128, MEM, 4096);
  k_gemm<<<dim3(8,96),256,0,stream>>>(MEM, 512, Wck, 512, 512, MCK, 512);
  k_gemm<<<dim3(8,96),256,0,stream>>>(MEM, 512, Wcv, 512, 512, MCV, 512);
  k_gemm<<<dim3(8,16),256,0,stream>>>(Wo, 512, Wcq, 512, 512, WCAT + (size_t)512*512, 512);
  k_copy<<<(512*512 + 255)/256, 256, 0, stream>>>(Wcq, WCAT, 512*512);
  k_init<<<NB,128,0,stream>>>(z_w, temb, XS, GF, IPH, CUR, TIP, POS, DONE, ACT);

  // ---- persistent decode: plain launch; 512 blocks, 2/CU co-resident ----
  DecP prm;
  prm.temb = temb; prm.Wq = Wq; prm.Wk = Wk; prm.Wv = Wv; prm.Wo = Wo;
  prm.Wco = Wco; prm.W1 = W1; prm.W2 = W2; prm.Wout = Wout;
  prm.MCK = MCK; prm.MCV = MCV; prm.WCAT = WCAT;
  prm.KC = KC; prm.VC = VC; prm.XS = XS; prm.X2 = X2; prm.X3 = X3; prm.X = X;
  prm.Qb = Qb; prm.CQ = CQ; prm.CA = CA; prm.H1 = H1; prm.PV = PV; prm.GF = GF;
  prm.PI = PI; prm.CUR = CUR; prm.TIP = TIP; prm.POS = POS; prm.DONE = DONE;
  prm.IPH = IPH; prm.ACT = ACT;
  prm.TOK = TOK; prm.GEN = GEN; prm.BND = BND; prm.HID = HID;
  prm.bar = (unsigned*)d_ws;

  k_decode<<<dim3(NBLK), dim3(256), 0, stream>>>(prm);
}

// Round 6
// 64248.212 us; speedup vs baseline: 4.5734x; 4.5734x over previous
//
#include <hip/hip_runtime.h>
#include <math.h>

#define NB 128
#define KPH 3
#define MAXPER 48
#define MAXTOK 144
#define LATENT 128
#define HD 512
#define NMEM 8
#define NH 8
#define VOC 8000
#define CT 145
#define NBLK 512
#define SCALE 0.125f

// ---- device-coherent (agent-scope, sc1: bypass XCD L2, hit MALL) access ----
__device__ __forceinline__ float ldsc(const float* p) {
  return __hip_atomic_load(const_cast<float*>(p), __ATOMIC_RELAXED, __HIP_MEMORY_SCOPE_AGENT);
}
__device__ __forceinline__ void stsc(float* p, float v) {
  __hip_atomic_store(p, v, __ATOMIC_RELAXED, __HIP_MEMORY_SCOPE_AGENT);
}
__device__ __forceinline__ int ldsci(const int* p) {
  return __hip_atomic_load(const_cast<int*>(p), __ATOMIC_RELAXED, __HIP_MEMORY_SCOPE_AGENT);
}
__device__ __forceinline__ void stsci(int* p, int v) {
  __hip_atomic_store(p, v, __ATOMIC_RELAXED, __HIP_MEMORY_SCOPE_AGENT);
}

// ======================= setup kernels (run once) ==========================

__global__ void k_zero(float* __restrict__ p, int n) {
  int i = blockIdx.x * blockDim.x + threadIdx.x;
  if (i < n) p[i] = 0.0f;
}

__global__ void k_wz(const float* __restrict__ z_seq, const float* __restrict__ zw,
                     float* __restrict__ out) {
  int i = blockIdx.x * blockDim.x + threadIdx.x;
  if (i < NB * KPH * LATENT) out[i] = zw[i >> 7] * z_seq[i];
}

__global__ void k_copy(const float* __restrict__ src, float* __restrict__ dst, int n) {
  int i = blockIdx.x * blockDim.x + threadIdx.x;
  if (i < n) dst[i] = src[i];
}

__global__ __launch_bounds__(256) void k_gemm(
    const float* __restrict__ A, int lda,
    const float* __restrict__ W, int ldw, int K,
    float* __restrict__ out, int ostride)
{
  __shared__ float As[32][36];
  __shared__ float Ws[32][64];
  const int t = threadIdx.x;
  const int c0 = blockIdx.x * 64, b0 = blockIdx.y * 32;
  const int c = t & 63, g = t >> 6;
  float acc[8] = {0,0,0,0,0,0,0,0};
  const int ra = t >> 3, ka = (t & 7) << 2;
  for (int k0 = 0; k0 < K; k0 += 32) {
    const float4 a4 = *reinterpret_cast<const float4*>(A + (size_t)(b0 + ra) * lda + k0 + ka);
    As[ra][ka] = a4.x; As[ra][ka+1] = a4.y; As[ra][ka+2] = a4.z; As[ra][ka+3] = a4.w;
    #pragma unroll
    for (int e = 0; e < 8; e++) {
      int li = t + e * 256;
      Ws[li >> 6][li & 63] = W[(size_t)(k0 + (li >> 6)) * ldw + c0 + (li & 63)];
    }
    __syncthreads();
    #pragma unroll
    for (int kk = 0; kk < 32; kk++) {
      float wv = Ws[kk][c];
      #pragma unroll
      for (int i = 0; i < 8; i++) acc[i] += As[g*8+i][kk] * wv;
    }
    __syncthreads();
  }
  #pragma unroll
  for (int i = 0; i < 8; i++)
    out[(size_t)(b0 + g * 8 + i) * ostride + c0 + c] = acc[i];
}

__global__ void k_init(const float* __restrict__ zw, const float* __restrict__ temb,
                       float* __restrict__ XS, float* __restrict__ gf, int* __restrict__ iph,
                       int* __restrict__ cur, int* __restrict__ tip, int* __restrict__ pos,
                       int* __restrict__ done, int* __restrict__ act)
{
  int b = blockIdx.x;
  if (threadIdx.x == 0) {
    int a0 = zw[b*3+0] > 0.01f;
    act[b*3+0] = a0;
    act[b*3+1] = zw[b*3+1] > 0.01f;
    act[b*3+2] = zw[b*3+2] > 0.01f;
    cur[b] = 0; tip[b] = 0; pos[b] = 0; done[b] = !a0;
    gf[b] = a0 ? 1.0f : 0.0f; iph[b] = 0;
  }
  for (int c = threadIdx.x; c < HD; c += blockDim.x)
    XS[(size_t)b * 1024 + c] = temb[1 * HD + c];   // BOS = 1
}

// ======================= persistent decode =================================

struct DecP {
  const float *temb, *Wq, *Wk, *Wv, *Wo, *Wco, *W1, *W2, *Wout;
  const float *MCK, *MCV, *WCAT;
  float *KC, *VC, *XS, *X2, *X3, *X, *Qb, *CQ, *CA, *H1, *PV, *GF;
  int *PI, *CUR, *TIP, *POS, *DONE, *IPH, *ACT;
  float *TOK, *GEN, *BND, *HID;
  unsigned *bar;
};

// R4 barrier (measured good): arrive on 8 spread counters, relaxed sum-poll.
__device__ __forceinline__ void gsync(unsigned* bars, unsigned target) {
  __syncthreads();
  if (threadIdx.x == 0) {
    __hip_atomic_fetch_add(&bars[(blockIdx.x & 7) * 32], 1u,
                           __ATOMIC_RELAXED, __HIP_MEMORY_SCOPE_AGENT);
    while (true) {
      unsigned sum = 0;
      #pragma unroll
      for (int i = 0; i < 8; i++)
        sum += __hip_atomic_load(&bars[i * 32], __ATOMIC_RELAXED, __HIP_MEMORY_SCOPE_AGENT);
      if (sum >= target) break;
      __builtin_amdgcn_s_sleep(4);
    }
  }
  __syncthreads();
}

__global__ __launch_bounds__(256, 2) void k_decode(DecP p) {
  __shared__ float As8[2][8][33];
  __shared__ float Ws[2][32][64];
  __shared__ float As32[2][32][36];
  __shared__ float rv[32][65];
  __shared__ float aux[4][224];
  __shared__ float sv[256];
  __shared__ int   si[256];
  __shared__ int   s_nxt;

  const int t = threadIdx.x;
  const int blk = blockIdx.x;
  unsigned tgt = 0;

  // 64col x 8row fp32 GEMM tile, 256 thr, 2-deep double-buffered pipeline.
  // A/R loads + out stores device-coherent (sc1); W loads L2-cached.
  // FP accumulation order per element identical to R4 (serial K per wave).
  auto gemm8 = [&](int bx, int by, const float* A, int lda,
                   const float* W, int ldw, int K,
                   const float* R, int rs,
                   float* out, int os, int oo, int dogelu) {
    const int c0 = bx * 64, b0 = by * 8;
    const int c = t & 63, g = t >> 6;
    const int ar = t >> 5, ac = t & 31;
    const int nslab = K >> 5;                 // >=16, even
    float acc0 = 0.f, acc1 = 0.f;
    const float* Ap = A + (size_t)(b0 + ar) * lda + ac;
    float a0r, a1r, w0r[8], w1r[8];
    a0r = ldsc(Ap);
    #pragma unroll
    for (int e = 0; e < 8; e++) {
      int li = t + e * 256;
      w0r[e] = W[(size_t)(li >> 6) * ldw + c0 + (li & 63)];
    }
    a1r = ldsc(Ap + 32);
    #pragma unroll
    for (int e = 0; e < 8; e++) {
      int li = t + e * 256;
      w1r[e] = W[(size_t)(32 + (li >> 6)) * ldw + c0 + (li & 63)];
    }
    for (int j = 0; j < nslab; j += 2) {
      // slab j -> buffer 0
      As8[0][ar][ac] = a0r;
      #pragma unroll
      for (int e = 0; e < 8; e++) {
        int li = t + e * 256;
        Ws[0][li >> 6][li & 63] = w0r[e];
      }
      __syncthreads();
      if (j + 2 < nslab) {
        a0r = ldsc(Ap + (j + 2) * 32);
        #pragma unroll
        for (int e = 0; e < 8; e++) {
          int li = t + e * 256;
          w0r[e] = W[(size_t)((j + 2) * 32 + (li >> 6)) * ldw + c0 + (li & 63)];
        }
      }
      #pragma unroll
      for (int kk = 0; kk < 32; kk++) {
        float wv = Ws[0][kk][c];
        acc0 += As8[0][g * 2 + 0][kk] * wv;
        acc1 += As8[0][g * 2 + 1][kk] * wv;
      }
      // slab j+1 -> buffer 1
      As8[1][ar][ac] = a1r;
      #pragma unroll
      for (int e = 0; e < 8; e++) {
        int li = t + e * 256;
        Ws[1][li >> 6][li & 63] = w1r[e];
      }
      __syncthreads();
      if (j + 3 < nslab) {
        a1r = ldsc(Ap + (j + 3) * 32);
        #pragma unroll
        for (int e = 0; e < 8; e++) {
          int li = t + e * 256;
          w1r[e] = W[(size_t)((j + 3) * 32 + (li >> 6)) * ldw + c0 + (li & 63)];
        }
      }
      #pragma unroll
      for (int kk = 0; kk < 32; kk++) {
        float wv = Ws[1][kk][c];
        acc0 += As8[1][g * 2 + 0][kk] * wv;
        acc1 += As8[1][g * 2 + 1][kk] * wv;
      }
    }
    #pragma unroll
    for (int i = 0; i < 2; i++) {
      float v = (i == 0) ? acc0 : acc1;
      int b = b0 + g * 2 + i;
      if (R) v += ldsc(R + (size_t)b * rs + c0 + c);
      if (dogelu) {
        float x3 = v * v * v;
        v = 0.5f * v * (1.0f + tanhf(0.7978845608028654f * (v + 0.044715f * x3)));
      }
      stsc(out + (size_t)b * os + oo + c0 + c, v);
    }
  };

  // logits tile 64col x 32row, K=512, 2-deep double-buffered + argmax partial
  auto logits_tile = [&](int bx, int by) {
    const int c0 = bx * 64, b0 = by * 32;
    const int c = t & 63, g = t >> 6;
    const int ra = t >> 3, ka = (t & 7) << 2;
    float acc[8] = {0,0,0,0,0,0,0,0};
    const float* Ap = p.X + (size_t)(b0 + ra) * 512 + ka;
    float a0r[4], a1r[4], w0r[8], w1r[8];
    #pragma unroll
    for (int u = 0; u < 4; u++) a0r[u] = ldsc(Ap + u);
    #pragma unroll
    for (int e = 0; e < 8; e++) {
      int li = t + e * 256;
      w0r[e] = p.Wout[(size_t)(li >> 6) * VOC + c0 + (li & 63)];
    }
    #pragma unroll
    for (int u = 0; u < 4; u++) a1r[u] = ldsc(Ap + 32 + u);
    #pragma unroll
    for (int e = 0; e < 8; e++) {
      int li = t + e * 256;
      w1r[e] = p.Wout[(size_t)(32 + (li >> 6)) * VOC + c0 + (li & 63)];
    }
    for (int j = 0; j < 16; j += 2) {
      // slab j -> buffer 0
      #pragma unroll
      for (int u = 0; u < 4; u++) As32[0][ra][ka + u] = a0r[u];
      #pragma unroll
      for (int e = 0; e < 8; e++) {
        int li = t + e * 256;
        Ws[0][li >> 6][li & 63] = w0r[e];
      }
      __syncthreads();
      if (j + 2 < 16) {
        #pragma unroll
        for (int u = 0; u < 4; u++) a0r[u] = ldsc(Ap + (j + 2) * 32 + u);
        #pragma unroll
        for (int e = 0; e < 8; e++) {
          int li = t + e * 256;
          w0r[e] = p.Wout[(size_t)((j + 2) * 32 + (li >> 6)) * VOC + c0 + (li & 63)];
        }
      }
      #pragma unroll
      for (int kk = 0; kk < 32; kk++) {
        float wv = Ws[0][kk][c];
        #pragma unroll
        for (int i = 0; i < 8; i++) acc[i] += As32[0][g*8+i][kk] * wv;
      }
      // slab j+1 -> buffer 1
      #pragma unroll
      for (int u = 0; u < 4; u++) As32[1][ra][ka + u] = a1r[u];
      #pragma unroll
      for (int e = 0; e < 8; e++) {
        int li = t + e * 256;
        Ws[1][li >> 6][li & 63] = w1r[e];
      }
      __syncthreads();
      if (j + 3 < 16) {
        #pragma unroll
        for (int u = 0; u < 4; u++) a1r[u] = ldsc(Ap + (j + 3) * 32 + u);
        #pragma unroll
        for (int e = 0; e < 8; e++) {
          int li = t + e * 256;
          w1r[e] = p.Wout[(size_t)((j + 3) * 32 + (li >> 6)) * VOC + c0 + (li & 63)];
        }
      }
      #pragma unroll
      for (int kk = 0; kk < 32; kk++) {
        float wv = Ws[1][kk][c];
        #pragma unroll
        for (int i = 0; i < 8; i++) acc[i] += As32[1][g*8+i][kk] * wv;
      }
    }
    #pragma unroll
    for (int i = 0; i < 8; i++) rv[g*8+i][c] = acc[i];
    __syncthreads();
    if (t < 32) {
      float best = rv[t][0]; int bi = 0;
      for (int cc = 1; cc < 64; cc++) {        // serial -> first-index tie-break
        float v = rv[t][cc];
        if (v > best) { best = v; bi = cc; }
      }
      stsc(&p.PV[(size_t)(b0 + t) * 125 + bx], best);
      stsci(&p.PI[(size_t)(b0 + t) * 125 + bx], c0 + bi);
    }
    __syncthreads();
  };

  for (int s = 0; s < MAXTOK; s++) {
    // ---- A: Q,K,V projections (slot s); bx = blk&7 == XCD -> W cols pinned ----
    if (blk < 128)
      gemm8(blk & 7, blk >> 3, p.XS, 1024, p.Wq, 512, 512, nullptr, 0, p.Qb, 512, 0, 0);
    else if (blk < 256)
      gemm8((blk-128) & 7, (blk-128) >> 3, p.XS, 1024, p.Wk, 512, 512, nullptr, 0, p.KC, CT*512, s*512, 0);
    else if (blk < 384)
      gemm8((blk-256) & 7, (blk-256) >> 3, p.XS, 1024, p.Wv, 512, 512, nullptr, 0, p.VC, CT*512, s*512, 0);
    tgt += NBLK; gsync(p.bar, tgt);

    // ---- B: self-attention, one wave per (b,h); b = XCD + 8k -> KV pinned ----
    if (blk < 256) {
      const int T = s + 1;
      int lane = t & 63, w = t >> 6;
      int u = (blk >> 3) * 4 + w;                  // [0,128) within this XCD
      int b = (blk & 7) + 8 * (u >> 3), h = u & 7; // b % 8 == XCD id
      float* ql = aux[w];
      float* sc = aux[w] + 64;
      ql[lane] = ldsc(&p.Qb[(size_t)b * 512 + h * 64 + lane]);
      __syncthreads();
      float lmax = -INFINITY;
      for (int s0 = lane; s0 < T; s0 += 64) {
        const float4* kp = reinterpret_cast<const float4*>(p.KC + ((size_t)b * CT + s0) * 512 + h * 64);
        float d = 0.0f;
        #pragma unroll
        for (int e = 0; e < 16; e++) {
          float4 k4 = kp[e];
          d += ql[4*e]*k4.x + ql[4*e+1]*k4.y + ql[4*e+2]*k4.z + ql[4*e+3]*k4.w;
        }
        d *= SCALE;
        sc[s0] = d;
        lmax = fmaxf(lmax, d);
      }
      #pragma unroll
      for (int off = 32; off; off >>= 1) lmax = fmaxf(lmax, __shfl_xor(lmax, off, 64));
      float lsum = 0.0f;
      for (int s0 = lane; s0 < T; s0 += 64) {
        float e = expf(sc[s0] - lmax);
        sc[s0] = e; lsum += e;
      }
      #pragma unroll
      for (int off = 32; off; off >>= 1) lsum += __shfl_xor(lsum, off, 64);
      __syncthreads();
      float inv = 1.0f / lsum;
      float acc = 0.0f;
      const float* vb = p.VC + (size_t)b * CT * 512 + h * 64 + lane;
      for (int s0 = 0; s0 < T; s0++) acc += sc[s0] * vb[(size_t)s0 * 512];
      stsc(&p.XS[(size_t)b * 1024 + 512 + h * 64 + lane], acc * inv);
    }
    tgt += NBLK; gsync(p.bar, tgt);

    // ---- C: X2 = XIN + SA@Wo ; CQ = [XIN|SA]@WCAT (K=1024 fused) ----
    if (blk < 128)
      gemm8(blk & 7, blk >> 3, p.XS + 512, 1024, p.Wo, 512, 512, p.XS, 1024, p.X2, 512, 0, 0);
    else if (blk < 256)
      gemm8((blk-128) & 7, (blk-128) >> 3, p.XS, 1024, p.WCAT, 512, 1024, nullptr, 0, p.CQ, 512, 0, 0);
    tgt += NBLK; gsync(p.bar, tgt);

    // ---- D: cross-attention, one block per b (b % 8 == XCD) ----
    if (blk < NB) {
      int b = blk;
      float* cqs = &As32[0][0][0];  // 512 floats
      float* scs = &rv[0][0];       // 64 floats
      cqs[t]       = ldsc(&p.CQ[(size_t)b * 512 + t]);
      cqs[t + 256] = ldsc(&p.CQ[(size_t)b * 512 + t + 256]);
      __syncthreads();
      float gate = ldsc(&p.GF[b]);
      int ip = ldsci(&p.IPH[b]);
      const float* mk = p.MCK + (size_t)(b * KPH + ip) * NMEM * 512;
      if (t < 64) {
        int h = t >> 3, m = t & 7;
        const float4* kp = reinterpret_cast<const float4*>(mk + m * 512 + h * 64);
        float d = 0.0f;
        #pragma unroll
        for (int e = 0; e < 16; e++) {
          float4 k4 = kp[e];
          d += cqs[h*64+4*e]*k4.x + cqs[h*64+4*e+1]*k4.y + cqs[h*64+4*e+2]*k4.z + cqs[h*64+4*e+3]*k4.w;
        }
        scs[t] = d * SCALE * gate;
      }
      __syncthreads();
      const float* mv = p.MCV + (size_t)(b * KPH + ip) * NMEM * 512;
      #pragma unroll
      for (int half = 0; half < 2; half++) {
        int c = t + half * 256;
        int h = c >> 6;
        float mx = scs[h*8];
        #pragma unroll
        for (int m = 1; m < 8; m++) mx = fmaxf(mx, scs[h*8+m]);
        float ee[8]; float sum = 0.0f;
        #pragma unroll
        for (int m = 0; m < 8; m++) { ee[m] = expf(scs[h*8+m] - mx); sum += ee[m]; }
        float a = 0.0f;
        #pragma unroll
        for (int m = 0; m < 8; m++) a += ee[m] * mv[(size_t)m * 512 + c];
        stsc(&p.CA[(size_t)b * 512 + c], gate * a / sum);
      }
    }
    tgt += NBLK; gsync(p.bar, tgt);

    // ---- E: X3 = X2 + CA@Wco ----
    if (blk < 128)
      gemm8(blk & 7, blk >> 3, p.CA, 512, p.Wco, 512, 512, p.X2, 512, p.X3, 512, 0, 0);
    tgt += NBLK; gsync(p.bar, tgt);

    // ---- F: H1 = gelu(X3@W1); bx = blk&31, bx%8 == XCD -> W1 pinned ----
    gemm8(blk & 31, blk >> 5, p.X3, 512, p.W1, 2048, 512, nullptr, 0, p.H1, 2048, 0, 1);
    tgt += NBLK; gsync(p.bar, tgt);

    // ---- G: X = X3 + H1@W2, K=2048 ----
    if (blk < 128)
      gemm8(blk & 7, blk >> 3, p.H1, 2048, p.W2, 512, 2048, p.X3, 512, p.X, 512, 0, 0);
    tgt += NBLK; gsync(p.bar, tgt);

    // ---- H: logits + argmax partials; col tile bx ≡ XCD (mod 8) ----
    {
      const int x = blk & 7, jj = blk >> 3;
      const int ii = jj & 15, by = jj >> 4;
      const int bx = x + 8 * ii;
      if (bx < 125) logits_tile(bx, by);
    }
    tgt += NBLK; gsync(p.bar, tgt);

    // ---- I: argmax finish + state machine + hiddens + next embedding ----
    if (blk < NB) {
      int b = blk;
      float v = -INFINITY; int idx = 0x7fffffff;
      if (t < 125) { v = ldsc(&p.PV[(size_t)b * 125 + t]); idx = ldsci(&p.PI[(size_t)b * 125 + t]); }
      sv[t] = v; si[t] = idx;
      __syncthreads();
      for (int s2 = 128; s2 > 0; s2 >>= 1) {
        if (t < s2) {
          float v2 = sv[t + s2]; int i2 = si[t + s2];
          if (v2 > sv[t] || (v2 == sv[t] && i2 < si[t])) { sv[t] = v2; si[t] = i2; }
        }
        __syncthreads();
      }
      if (t == 0) {
        int nxt = si[0]; s_nxt = nxt;
        int dn = p.DONE[b]; int live = !dn;
        int pp = p.POS[b], tp = p.TIP[b], cp = p.CUR[b];
        if (pp < MAXTOK) {
          p.TOK[(size_t)b * MAXTOK + pp] = live ? (float)nxt : 0.0f;
          p.GEN[(size_t)b * MAXTOK + pp] = live ? 1.0f : 0.0f;
        }
        pp += live; tp += live;
        int eos = (nxt == 2) && (tp >= 1);
        int sw = (eos || (tp >= MAXPER)) && live;
        cp += sw;
        if (sw) tp = 0;
        int cpc = cp < 2 ? cp : 2;
        if (sw && (cp < KPH)) p.BND[(size_t)b * KPH + cpc] = (float)pp;
        dn = dn || (cp >= KPH) || (sw && !p.ACT[b*3 + cpc]);
        p.CUR[b] = cp; p.TIP[b] = tp; p.POS[b] = pp; p.DONE[b] = dn;
        stsc(&p.GF[b], (p.ACT[b*3 + cpc] && !dn) ? 1.0f : 0.0f);
        stsci(&p.IPH[b], cpc);
      }
      __syncthreads();
      int nxt = s_nxt;
      #pragma unroll
      for (int rep = 0; rep < 2; rep++) {
        int c = t + rep * 256;
        stsc(&p.XS[(size_t)b * 1024 + c], p.temb[(size_t)nxt * 512 + c]);
        p.HID[((size_t)s * NB + b) * 512 + c] = ldsc(&p.X[(size_t)b * 512 + c]);
      }
    }
    tgt += NBLK; gsync(p.bar, tgt);
  }
}

// ======================= host ==============================================

extern "C" void kernel_launch(void* const* d_in, const int* in_sizes, int n_in,
                              void* d_out, int out_size, void* d_ws, size_t ws_size,
                              hipStream_t stream)
{
  const float* z_seq = (const float*)d_in[0];
  const float* z_w   = (const float*)d_in[1];
  const float* W_l2d = (const float*)d_in[2];
  const float* temb  = (const float*)d_in[3];
  const float* Wq  = (const float*)d_in[4];
  const float* Wk  = (const float*)d_in[5];
  const float* Wv  = (const float*)d_in[6];
  const float* Wo  = (const float*)d_in[7];
  const float* Wcq = (const float*)d_in[8];
  const float* Wck = (const float*)d_in[9];
  const float* Wcv = (const float*)d_in[10];
  const float* Wco = (const float*)d_in[11];
  const float* W1  = (const float*)d_in[12];
  const float* W2  = (const float*)d_in[13];
  const float* Wout= (const float*)d_in[14];

  float* fw = (float*)d_ws;
  size_t o = 256;   // first 256 words: spread barrier counters
  auto alloc = [&](size_t n) { float* r = fw + o; o += (n + 63) & ~(size_t)63; return r; };
  float* MCK = alloc((size_t)NB*KPH*NMEM*HD);
  float* MCV = alloc((size_t)NB*KPH*NMEM*HD);
  float* MEM = alloc((size_t)NB*KPH*NMEM*HD);   // reused as WCAT after setup
  float* KC  = alloc((size_t)NB*CT*HD);
  float* VC  = alloc((size_t)NB*CT*HD);
  float* XS  = alloc((size_t)NB*1024);          // [XIN | SA]
  float* X2  = alloc((size_t)NB*HD);
  float* X3  = alloc((size_t)NB*HD);
  float* X   = alloc((size_t)NB*HD);
  float* Qb  = alloc((size_t)NB*HD);
  float* CQ  = alloc((size_t)NB*HD);
  float* CA  = alloc((size_t)NB*HD);
  float* H1  = alloc((size_t)NB*4*HD);
  float* WZ  = alloc((size_t)NB*KPH*LATENT);
  float* PV  = alloc((size_t)NB*125);
  float* GF  = alloc(NB);
  int* ib = (int*)alloc(0);
  size_t io = 0;
  auto ialloc = [&](size_t n) { int* r = ib + io; io += (n + 63) & ~(size_t)63; return r; };
  int* PI  = ialloc((size_t)NB*125);
  int* CUR = ialloc(NB);
  int* TIP = ialloc(NB);
  int* POS = ialloc(NB);
  int* DONE= ialloc(NB);
  int* IPH = ialloc(NB);
  int* ACT = ialloc(NB*KPH);

  float* WCAT = MEM;   // [Wcq ; Wo@Wcq]  (1024 x 512) — overlays MEM after setup

  float* out_f = (float*)d_out;
  float* TOK  = out_f;
  float* GEN  = out_f + NB*MAXTOK;
  float* BND  = out_f + 2*NB*MAXTOK;
  float* HID  = out_f + 2*NB*MAXTOK + NB*KPH;

  // ---- one-time setup (plain kernels; dispatch boundaries give coherence) ----
  k_zero<<<1, 256, 0, stream>>>(fw, 256);                                 // barrier
  int nz = 2*NB*MAXTOK + NB*KPH;
  k_zero<<<(nz + 255)/256, 256, 0, stream>>>(out_f, nz);                  // tok/gen/bnd
  k_wz<<<(NB*KPH*LATENT + 255)/256, 256, 0, stream>>>(z_seq, z_w, WZ);
  k_gemm<<<dim3(64,12),256,0,stream>>>(WZ, 128, W_l2d, 4096, 128, MEM, 4096);
  k_gemm<<<dim3(8,96),256,0,stream>>>(MEM, 512, Wck, 512, 512, MCK, 512);
  k_gemm<<<dim3(8,96),256,0,stream>>>(MEM, 512, Wcv, 512, 512, MCV, 512);
  k_gemm<<<dim3(8,16),256,0,stream>>>(Wo, 512, Wcq, 512, 512, WCAT + (size_t)512*512, 512);
  k_copy<<<(512*512 + 255)/256, 256, 0, stream>>>(Wcq, WCAT, 512*512);
  k_init<<<NB,128,0,stream>>>(z_w, temb, XS, GF, IPH, CUR, TIP, POS, DONE, ACT);

  // ---- persistent decode: plain launch; 512 blocks, 2/CU co-resident ----
  DecP prm;
  prm.temb = temb; prm.Wq = Wq; prm.Wk = Wk; prm.Wv = Wv; prm.Wo = Wo;
  prm.Wco = Wco; prm.W1 = W1; prm.W2 = W2; prm.Wout = Wout;
  prm.MCK = MCK; prm.MCV = MCV; prm.WCAT = WCAT;
  prm.KC = KC; prm.VC = VC; prm.XS = XS; prm.X2 = X2; prm.X3 = X3; prm.X = X;
  prm.Qb = Qb; prm.CQ = CQ; prm.CA = CA; prm.H1 = H1; prm.PV = PV; prm.GF = GF;
  prm.PI = PI; prm.CUR = CUR; prm.TIP = TIP; prm.POS = POS; prm.DONE = DONE;
  prm.IPH = IPH; prm.ACT = ACT;
  prm.TOK = TOK; prm.GEN = GEN; prm.BND = BND; prm.HID = HID;
  prm.bar = (unsigned*)d_ws;

  k_decode<<<dim3(NBLK), dim3(256), 0, stream>>>(prm);
}

// Round 7
// 36413.571 us; speedup vs baseline: 8.0693x; 1.7644x over previous
//
#include <hip/hip_runtime.h>
#include <math.h>

#define NB 128
#define KPH 3
#define MAXPER 48
#define MAXTOK 144
#define LATENT 128
#define HD 512
#define NMEM 8
#define NH 8
#define VOC 8000
#define CT 145
#define NBLK 512
#define SCALE 0.125f

// ---- device-coherent (agent-scope: bypass XCD L2, hit MALL) access ----
__device__ __forceinline__ float ldsc(const float* p) {
  return __hip_atomic_load(const_cast<float*>(p), __ATOMIC_RELAXED, __HIP_MEMORY_SCOPE_AGENT);
}
__device__ __forceinline__ void stsc(float* p, float v) {
  __hip_atomic_store(p, v, __ATOMIC_RELAXED, __HIP_MEMORY_SCOPE_AGENT);
}
__device__ __forceinline__ int ldsci(const int* p) {
  return __hip_atomic_load(const_cast<int*>(p), __ATOMIC_RELAXED, __HIP_MEMORY_SCOPE_AGENT);
}
__device__ __forceinline__ void stsci(int* p, int v) {
  __hip_atomic_store(p, v, __ATOMIC_RELAXED, __HIP_MEMORY_SCOPE_AGENT);
}

// global -> LDS async DMA, 4 B/lane, wave-uniform LDS base + lane*4
__device__ __forceinline__ void gload_lds(const float* g, float* l) {
  __builtin_amdgcn_global_load_lds(
      (const __attribute__((address_space(1))) unsigned int*)g,
      (__attribute__((address_space(3))) unsigned int*)l, 4, 0, 0);
}

// ======================= setup kernels (run once) ==========================

__global__ void k_zero(float* __restrict__ p, int n) {
  int i = blockIdx.x * blockDim.x + threadIdx.x;
  if (i < n) p[i] = 0.0f;
}

__global__ void k_wz(const float* __restrict__ z_seq, const float* __restrict__ zw,
                     float* __restrict__ out) {
  int i = blockIdx.x * blockDim.x + threadIdx.x;
  if (i < NB * KPH * LATENT) out[i] = zw[i >> 7] * z_seq[i];
}

__global__ void k_copy(const float* __restrict__ src, float* __restrict__ dst, int n) {
  int i = blockIdx.x * blockDim.x + threadIdx.x;
  if (i < n) dst[i] = src[i];
}

__global__ __launch_bounds__(256) void k_gemm(
    const float* __restrict__ A, int lda,
    const float* __restrict__ W, int ldw, int K,
    float* __restrict__ out, int ostride)
{
  __shared__ float As[32][36];
  __shared__ float Ws[32][64];
  const int t = threadIdx.x;
  const int c0 = blockIdx.x * 64, b0 = blockIdx.y * 32;
  const int c = t & 63, g = t >> 6;
  float acc[8] = {0,0,0,0,0,0,0,0};
  const int ra = t >> 3, ka = (t & 7) << 2;
  for (int k0 = 0; k0 < K; k0 += 32) {
    const float4 a4 = *reinterpret_cast<const float4*>(A + (size_t)(b0 + ra) * lda + k0 + ka);
    As[ra][ka] = a4.x; As[ra][ka+1] = a4.y; As[ra][ka+2] = a4.z; As[ra][ka+3] = a4.w;
    #pragma unroll
    for (int e = 0; e < 8; e++) {
      int li = t + e * 256;
      Ws[li >> 6][li & 63] = W[(size_t)(k0 + (li >> 6)) * ldw + c0 + (li & 63)];
    }
    __syncthreads();
    #pragma unroll
    for (int kk = 0; kk < 32; kk++) {
      float wv = Ws[kk][c];
      #pragma unroll
      for (int i = 0; i < 8; i++) acc[i] += As[g*8+i][kk] * wv;
    }
    __syncthreads();
  }
  #pragma unroll
  for (int i = 0; i < 8; i++)
    out[(size_t)(b0 + g * 8 + i) * ostride + c0 + c] = acc[i];
}

__global__ void k_init(const float* __restrict__ zw, const float* __restrict__ temb,
                       float* __restrict__ XS, float* __restrict__ gf, int* __restrict__ iph,
                       int* __restrict__ cur, int* __restrict__ tip, int* __restrict__ pos,
                       int* __restrict__ done, int* __restrict__ act)
{
  int b = blockIdx.x;
  if (threadIdx.x == 0) {
    int a0 = zw[b*3+0] > 0.01f;
    act[b*3+0] = a0;
    act[b*3+1] = zw[b*3+1] > 0.01f;
    act[b*3+2] = zw[b*3+2] > 0.01f;
    cur[b] = 0; tip[b] = 0; pos[b] = 0; done[b] = !a0;
    gf[b] = a0 ? 1.0f : 0.0f; iph[b] = 0;
  }
  for (int c = threadIdx.x; c < HD; c += blockDim.x)
    XS[(size_t)b * 1024 + c] = temb[1 * HD + c];   // BOS = 1
}

// ======================= persistent decode =================================

struct DecP {
  const float *temb, *Wq, *Wk, *Wv, *Wo, *Wco, *W1, *W2, *Wout;
  const float *MCK, *MCV, *WCAT;
  float *KC, *VC, *XS, *X2, *X3, *X, *Qb, *CQ, *CA, *H1, *PV, *GF;
  int *PI, *CUR, *TIP, *POS, *DONE, *IPH, *ACT;
  float *TOK, *GEN, *BND, *HID;
  unsigned *bar;
};

// R4 barrier (measured good): arrive on 8 spread counters, relaxed sum-poll.
__device__ __forceinline__ void gsync(unsigned* bars, unsigned target) {
  __syncthreads();
  if (threadIdx.x == 0) {
    __hip_atomic_fetch_add(&bars[(blockIdx.x & 7) * 32], 1u,
                           __ATOMIC_RELAXED, __HIP_MEMORY_SCOPE_AGENT);
    while (true) {
      unsigned sum = 0;
      #pragma unroll
      for (int i = 0; i < 8; i++)
        sum += __hip_atomic_load(&bars[i * 32], __ATOMIC_RELAXED, __HIP_MEMORY_SCOPE_AGENT);
      if (sum >= target) break;
      __builtin_amdgcn_s_sleep(4);
    }
  }
  __syncthreads();
}

__global__ __launch_bounds__(256, 2) void k_decode(DecP p) {
  __shared__ float Ws2[2][64][64];     // W slab, async-DMA double-buffered (32 KB)
  __shared__ float As2[2][8][72];      // A slab for 8-row GEMMs
  __shared__ float AsL[2][32][72];     // A slab for logits (32-row)
  __shared__ float rv[32][65];
  __shared__ float aux[4][224];
  __shared__ float sv[256];
  __shared__ int   si[256];
  __shared__ int   s_nxt;

  const int t = threadIdx.x;
  const int blk = blockIdx.x;
  unsigned tgt = 0;

  // 64col x 8row fp32 GEMM, slab K=64, W via global_load_lds double-buffer.
  // Per-output FP accumulation: serial kk over full K (bit-identical to R4).
  auto gemm8 = [&](int bx, int by, const float* A, int lda,
                   const float* W, int ldw, int K,
                   const float* R, int rs,
                   float* out, int os, int oo, int dogelu) {
    const int c0 = bx * 64, b0 = by * 8;
    const int c = t & 63, g = t >> 6;
    const int ar = t & 7, ak = t >> 3;          // A staging: row, k(0..31)
    const int nslab = K >> 6;
    float acc0 = 0.f, acc1 = 0.f;
    float res0 = 0.f, res1 = 0.f;
    if (R) {
      res0 = ldsc(R + (size_t)(b0 + g * 2 + 0) * rs + c0 + c);
      res1 = ldsc(R + (size_t)(b0 + g * 2 + 1) * rs + c0 + c);
    }
    // prologue: A(0) regs (issued first -> oldest), W(0) DMA -> buf0
    float aR0 = ldsc(A + (size_t)(b0 + ar) * lda + ak);
    float aR1 = ldsc(A + (size_t)(b0 + ar) * lda + 32 + ak);
    #pragma unroll
    for (int e = 0; e < 16; e++)
      gload_lds(W + (size_t)(g * 16 + e) * ldw + c0 + c, &Ws2[0][g * 16 + e][0]);
    for (int j = 0; j < nslab; j++) {
      const int cur = j & 1;
      As2[cur][ar][ak] = aR0;                  // waits A regs only (vmcnt partial)
      As2[cur][ar][ak + 32] = aR1;
      __syncthreads();                         // drains W(j) DMA
      if (j + 1 < nslab) {
        aR0 = ldsc(A + (size_t)(b0 + ar) * lda + (j + 1) * 64 + ak);
        aR1 = ldsc(A + (size_t)(b0 + ar) * lda + (j + 1) * 64 + 32 + ak);
        #pragma unroll
        for (int e = 0; e < 16; e++)
          gload_lds(W + (size_t)((j + 1) * 64 + g * 16 + e) * ldw + c0 + c,
                    &Ws2[cur ^ 1][g * 16 + e][0]);
      }
      #pragma unroll
      for (int kk = 0; kk < 64; kk++) {
        float wv = Ws2[cur][kk][c];
        acc0 += As2[cur][g * 2 + 0][kk] * wv;
        acc1 += As2[cur][g * 2 + 1][kk] * wv;
      }
    }
    #pragma unroll
    for (int i = 0; i < 2; i++) {
      float v = (i == 0) ? acc0 : acc1;
      int b = b0 + g * 2 + i;
      v += (i == 0) ? res0 : res1;
      if (dogelu) {
        float x3 = v * v * v;
        v = 0.5f * v * (1.0f + tanhf(0.7978845608028654f * (v + 0.044715f * x3)));
      }
      stsc(out + (size_t)b * os + oo + c0 + c, v);
    }
  };

  // logits tile 64col x 32row, K=512 (8 slabs of 64), same async-W pipeline.
  auto logits_tile = [&](int bx, int by) {
    const int c0 = bx * 64, b0 = by * 32;
    const int c = t & 63, g = t >> 6;
    const int ar = t & 31, akb = (t >> 5) * 8;  // A staging: row, k-base
    float acc[8] = {0,0,0,0,0,0,0,0};
    float aR[8];
    const float* Ab = p.X + (size_t)(b0 + ar) * 512 + akb;
    #pragma unroll
    for (int u = 0; u < 8; u++) aR[u] = ldsc(Ab + u);
    #pragma unroll
    for (int e = 0; e < 16; e++)
      gload_lds(p.Wout + (size_t)(g * 16 + e) * VOC + c0 + c, &Ws2[0][g * 16 + e][0]);
    for (int j = 0; j < 8; j++) {
      const int cur = j & 1;
      #pragma unroll
      for (int u = 0; u < 8; u++) AsL[cur][ar][akb + u] = aR[u];
      __syncthreads();
      if (j + 1 < 8) {
        #pragma unroll
        for (int u = 0; u < 8; u++) aR[u] = ldsc(Ab + (j + 1) * 64 + u);
        #pragma unroll
        for (int e = 0; e < 16; e++)
          gload_lds(p.Wout + (size_t)((j + 1) * 64 + g * 16 + e) * VOC + c0 + c,
                    &Ws2[cur ^ 1][g * 16 + e][0]);
      }
      #pragma unroll
      for (int kk = 0; kk < 64; kk++) {
        float wv = Ws2[cur][kk][c];
        #pragma unroll
        for (int i = 0; i < 8; i++) acc[i] += AsL[cur][g * 8 + i][kk] * wv;
      }
    }
    #pragma unroll
    for (int i = 0; i < 8; i++) rv[g*8+i][c] = acc[i];
    __syncthreads();
    if (t < 32) {
      float best = rv[t][0]; int bi = 0;
      for (int cc = 1; cc < 64; cc++) {        // serial -> first-index tie-break
        float v = rv[t][cc];
        if (v > best) { best = v; bi = cc; }
      }
      stsc(&p.PV[(size_t)(b0 + t) * 125 + bx], best);
      stsci(&p.PI[(size_t)(b0 + t) * 125 + bx], c0 + bi);
    }
    __syncthreads();
  };

  for (int s = 0; s < MAXTOK; s++) {
    // ---- A: Q,K,V projections (slot s) ----
    if (blk < 128)
      gemm8(blk & 7, blk >> 3, p.XS, 1024, p.Wq, 512, 512, nullptr, 0, p.Qb, 512, 0, 0);
    else if (blk < 256)
      gemm8((blk-128) & 7, (blk-128) >> 3, p.XS, 1024, p.Wk, 512, 512, nullptr, 0, p.KC, CT*512, s*512, 0);
    else if (blk < 384)
      gemm8((blk-256) & 7, (blk-256) >> 3, p.XS, 1024, p.Wv, 512, 512, nullptr, 0, p.VC, CT*512, s*512, 0);
    tgt += NBLK; gsync(p.bar, tgt);

    // ---- B: self-attention, T = s+1, one wave per (b,h) (R4 map) ----
    if (blk < 256) {
      const int T = s + 1;
      int lane = t & 63, w = t >> 6;
      int task = blk * 4 + w, b = task >> 3, h = task & 7;
      float* ql = aux[w];
      float* sc = aux[w] + 64;
      ql[lane] = ldsc(&p.Qb[(size_t)b * 512 + h * 64 + lane]);
      __syncthreads();
      float lmax = -INFINITY;
      for (int s0 = lane; s0 < T; s0 += 64) {
        const float4* kp = reinterpret_cast<const float4*>(p.KC + ((size_t)b * CT + s0) * 512 + h * 64);
        float d = 0.0f;
        #pragma unroll
        for (int e = 0; e < 16; e++) {
          float4 k4 = kp[e];
          d += ql[4*e]*k4.x + ql[4*e+1]*k4.y + ql[4*e+2]*k4.z + ql[4*e+3]*k4.w;
        }
        d *= SCALE;
        sc[s0] = d;
        lmax = fmaxf(lmax, d);
      }
      #pragma unroll
      for (int off = 32; off; off >>= 1) lmax = fmaxf(lmax, __shfl_xor(lmax, off, 64));
      float lsum = 0.0f;
      for (int s0 = lane; s0 < T; s0 += 64) {
        float e = expf(sc[s0] - lmax);
        sc[s0] = e; lsum += e;
      }
      #pragma unroll
      for (int off = 32; off; off >>= 1) lsum += __shfl_xor(lsum, off, 64);
      __syncthreads();
      float inv = 1.0f / lsum;
      float acc = 0.0f;
      const float* vb = p.VC + (size_t)b * CT * 512 + h * 64 + lane;
      for (int s0 = 0; s0 < T; s0++) acc += sc[s0] * vb[(size_t)s0 * 512];
      stsc(&p.XS[(size_t)b * 1024 + 512 + h * 64 + lane], acc * inv);
    }
    tgt += NBLK; gsync(p.bar, tgt);

    // ---- C: X2 = XIN + SA@Wo ; CQ = [XIN|SA]@WCAT (K=1024 fused) ----
    if (blk < 128)
      gemm8(blk & 7, blk >> 3, p.XS + 512, 1024, p.Wo, 512, 512, p.XS, 1024, p.X2, 512, 0, 0);
    else if (blk < 256)
      gemm8((blk-128) & 7, (blk-128) >> 3, p.XS, 1024, p.WCAT, 512, 1024, nullptr, 0, p.CQ, 512, 0, 0);
    tgt += NBLK; gsync(p.bar, tgt);

    // ---- D: cross-attention, one block per b ----
    if (blk < NB) {
      int b = blk;
      float* cqs = &AsL[0][0][0];   // 512 floats
      float* scs = &rv[0][0];       // 64 floats
      cqs[t]       = ldsc(&p.CQ[(size_t)b * 512 + t]);
      cqs[t + 256] = ldsc(&p.CQ[(size_t)b * 512 + t + 256]);
      __syncthreads();
      float gate = ldsc(&p.GF[b]);
      int ip = ldsci(&p.IPH[b]);
      const float* mk = p.MCK + (size_t)(b * KPH + ip) * NMEM * 512;
      if (t < 64) {
        int h = t >> 3, m = t & 7;
        const float4* kp = reinterpret_cast<const float4*>(mk + m * 512 + h * 64);
        float d = 0.0f;
        #pragma unroll
        for (int e = 0; e < 16; e++) {
          float4 k4 = kp[e];
          d += cqs[h*64+4*e]*k4.x + cqs[h*64+4*e+1]*k4.y + cqs[h*64+4*e+2]*k4.z + cqs[h*64+4*e+3]*k4.w;
        }
        scs[t] = d * SCALE * gate;
      }
      __syncthreads();
      const float* mv = p.MCV + (size_t)(b * KPH + ip) * NMEM * 512;
      #pragma unroll
      for (int half = 0; half < 2; half++) {
        int c = t + half * 256;
        int h = c >> 6;
        float mx = scs[h*8];
        #pragma unroll
        for (int m = 1; m < 8; m++) mx = fmaxf(mx, scs[h*8+m]);
        float ee[8]; float sum = 0.0f;
        #pragma unroll
        for (int m = 0; m < 8; m++) { ee[m] = expf(scs[h*8+m] - mx); sum += ee[m]; }
        float a = 0.0f;
        #pragma unroll
        for (int m = 0; m < 8; m++) a += ee[m] * mv[(size_t)m * 512 + c];
        stsc(&p.CA[(size_t)b * 512 + c], gate * a / sum);
      }
    }
    tgt += NBLK; gsync(p.bar, tgt);

    // ---- E: X3 = X2 + CA@Wco ----
    if (blk < 128)
      gemm8(blk & 7, blk >> 3, p.CA, 512, p.Wco, 512, 512, p.X2, 512, p.X3, 512, 0, 0);
    tgt += NBLK; gsync(p.bar, tgt);

    // ---- F: H1 = gelu(X3@W1), N=2048, all 512 blocks ----
    gemm8(blk & 31, blk >> 5, p.X3, 512, p.W1, 2048, 512, nullptr, 0, p.H1, 2048, 0, 1);
    tgt += NBLK; gsync(p.bar, tgt);

    // ---- G: X = X3 + H1@W2, K=2048 ----
    if (blk < 128)
      gemm8(blk & 7, blk >> 3, p.H1, 2048, p.W2, 512, 2048, p.X3, 512, p.X, 512, 0, 0);
    tgt += NBLK; gsync(p.bar, tgt);

    // ---- H: logits + argmax partials, 500 tiles (R4 linear map) ----
    if (blk < 500) logits_tile(blk % 125, blk / 125);
    tgt += NBLK; gsync(p.bar, tgt);

    // ---- I: argmax finish + state machine + hiddens + next embedding ----
    if (blk < NB) {
      int b = blk;
      float v = -INFINITY; int idx = 0x7fffffff;
      if (t < 125) { v = ldsc(&p.PV[(size_t)b * 125 + t]); idx = ldsci(&p.PI[(size_t)b * 125 + t]); }
      sv[t] = v; si[t] = idx;
      __syncthreads();
      for (int s2 = 128; s2 > 0; s2 >>= 1) {
        if (t < s2) {
          float v2 = sv[t + s2]; int i2 = si[t + s2];
          if (v2 > sv[t] || (v2 == sv[t] && i2 < si[t])) { sv[t] = v2; si[t] = i2; }
        }
        __syncthreads();
      }
      if (t == 0) {
        int nxt = si[0]; s_nxt = nxt;
        int dn = p.DONE[b]; int live = !dn;
        int pp = p.POS[b], tp = p.TIP[b], cp = p.CUR[b];
        if (pp < MAXTOK) {
          p.TOK[(size_t)b * MAXTOK + pp] = live ? (float)nxt : 0.0f;
          p.GEN[(size_t)b * MAXTOK + pp] = live ? 1.0f : 0.0f;
        }
        pp += live; tp += live;
        int eos = (nxt == 2) && (tp >= 1);
        int sw = (eos || (tp >= MAXPER)) && live;
        cp += sw;
        if (sw) tp = 0;
        int cpc = cp < 2 ? cp : 2;
        if (sw && (cp < KPH)) p.BND[(size_t)b * KPH + cpc] = (float)pp;
        dn = dn || (cp >= KPH) || (sw && !p.ACT[b*3 + cpc]);
        p.CUR[b] = cp; p.TIP[b] = tp; p.POS[b] = pp; p.DONE[b] = dn;
        stsc(&p.GF[b], (p.ACT[b*3 + cpc] && !dn) ? 1.0f : 0.0f);
        stsci(&p.IPH[b], cpc);
      }
      __syncthreads();
      int nxt = s_nxt;
      #pragma unroll
      for (int rep = 0; rep < 2; rep++) {
        int c = t + rep * 256;
        stsc(&p.XS[(size_t)b * 1024 + c], p.temb[(size_t)nxt * 512 + c]);
        p.HID[((size_t)s * NB + b) * 512 + c] = ldsc(&p.X[(size_t)b * 512 + c]);
      }
    }
    tgt += NBLK; gsync(p.bar, tgt);
  }
}

// ======================= host ==============================================

extern "C" void kernel_launch(void* const* d_in, const int* in_sizes, int n_in,
                              void* d_out, int out_size, void* d_ws, size_t ws_size,
                              hipStream_t stream)
{
  const float* z_seq = (const float*)d_in[0];
  const float* z_w   = (const float*)d_in[1];
  const float* W_l2d = (const float*)d_in[2];
  const float* temb  = (const float*)d_in[3];
  const float* Wq  = (const float*)d_in[4];
  const float* Wk  = (const float*)d_in[5];
  const float* Wv  = (const float*)d_in[6];
  const float* Wo  = (const float*)d_in[7];
  const float* Wcq = (const float*)d_in[8];
  const float* Wck = (const float*)d_in[9];
  const float* Wcv = (const float*)d_in[10];
  const float* Wco = (const float*)d_in[11];
  const float* W1  = (const float*)d_in[12];
  const float* W2  = (const float*)d_in[13];
  const float* Wout= (const float*)d_in[14];

  float* fw = (float*)d_ws;
  size_t o = 256;   // first 256 words: spread barrier counters
  auto alloc = [&](size_t n) { float* r = fw + o; o += (n + 63) & ~(size_t)63; return r; };
  float* MCK = alloc((size_t)NB*KPH*NMEM*HD);
  float* MCV = alloc((size_t)NB*KPH*NMEM*HD);
  float* MEM = alloc((size_t)NB*KPH*NMEM*HD);   // reused as WCAT after setup
  float* KC  = alloc((size_t)NB*CT*HD);
  float* VC  = alloc((size_t)NB*CT*HD);
  float* XS  = alloc((size_t)NB*1024);          // [XIN | SA]
  float* X2  = alloc((size_t)NB*HD);
  float* X3  = alloc((size_t)NB*HD);
  float* X   = alloc((size_t)NB*HD);
  float* Qb  = alloc((size_t)NB*HD);
  float* CQ  = alloc((size_t)NB*HD);
  float* CA  = alloc((size_t)NB*HD);
  float* H1  = alloc((size_t)NB*4*HD);
  float* WZ  = alloc((size_t)NB*KPH*LATENT);
  float* PV  = alloc((size_t)NB*125);
  float* GF  = alloc(NB);
  int* ib = (int*)alloc(0);
  size_t io = 0;
  auto ialloc = [&](size_t n) { int* r = ib + io; io += (n + 63) & ~(size_t)63; return r; };
  int* PI  = ialloc((size_t)NB*125);
  int* CUR = ialloc(NB);
  int* TIP = ialloc(NB);
  int* POS = ialloc(NB);
  int* DONE= ialloc(NB);
  int* IPH = ialloc(NB);
  int* ACT = ialloc(NB*KPH);

  float* WCAT = MEM;   // [Wcq ; Wo@Wcq]  (1024 x 512) — overlays MEM after setup

  float* out_f = (float*)d_out;
  float* TOK  = out_f;
  float* GEN  = out_f + NB*MAXTOK;
  float* BND  = out_f + 2*NB*MAXTOK;
  float* HID  = out_f + 2*NB*MAXTOK + NB*KPH;

  // ---- one-time setup (plain kernels; dispatch boundaries give coherence) ----
  k_zero<<<1, 256, 0, stream>>>(fw, 256);                                 // barrier
  int nz = 2*NB*MAXTOK + NB*KPH;
  k_zero<<<(nz + 255)/256, 256, 0, stream>>>(out_f, nz);                  // tok/gen/bnd
  k_wz<<<(NB*KPH*LATENT + 255)/256, 256, 0, stream>>>(z_seq, z_w, WZ);
  k_gemm<<<dim3(64,12),256,0,stream>>>(WZ, 128, W_l2d, 4096, 128, MEM, 4096);
  k_gemm<<<dim3(8,96),256,0,stream>>>(MEM, 512, Wck, 512, 512, MCK, 512);
  k_gemm<<<dim3(8,96),256,0,stream>>>(MEM, 512, Wcv, 512, 512, MCV, 512);
  k_gemm<<<dim3(8,16),256,0,stream>>>(Wo, 512, Wcq, 512, 512, WCAT + (size_t)512*512, 512);
  k_copy<<<(512*512 + 255)/256, 256, 0, stream>>>(Wcq, WCAT, 512*512);
  k_init<<<NB,128,0,stream>>>(z_w, temb, XS, GF, IPH, CUR, TIP, POS, DONE, ACT);

  // ---- persistent decode: plain launch; 512 blocks, 2/CU co-resident ----
  DecP prm;
  prm.temb = temb; prm.Wq = Wq; prm.Wk = Wk; prm.Wv = Wv; prm.Wo = Wo;
  prm.Wco = Wco; prm.W1 = W1; prm.W2 = W2; prm.Wout = Wout;
  prm.MCK = MCK; prm.MCV = MCV; prm.WCAT = WCAT;
  prm.KC = KC; prm.VC = VC; prm.XS = XS; prm.X2 = X2; prm.X3 = X3; prm.X = X;
  prm.Qb = Qb; prm.CQ = CQ; prm.CA = CA; prm.H1 = H1; prm.PV = PV; prm.GF = GF;
  prm.PI = PI; prm.CUR = CUR; prm.TIP = TIP; prm.POS = POS; prm.DONE = DONE;
  prm.IPH = IPH; prm.ACT = ACT;
  prm.TOK = TOK; prm.GEN = GEN; prm.BND = BND; prm.HID = HID;
  prm.bar = (unsigned*)d_ws;

  k_decode<<<dim3(NBLK), dim3(256), 0, stream>>>(prm);
}

// Round 8
// 33270.398 us; speedup vs baseline: 8.8317x; 1.0945x over previous
//
#include <hip/hip_runtime.h>
#include <math.h>

#define NB 128
#define KPH 3
#define MAXPER 48
#define MAXTOK 144
#define LATENT 128
#define HD 512
#define NMEM 8
#define NH 8
#define VOC 8000
#define CT 145
#define NBLK 512
#define SCALE 0.125f

// ---- device-coherent (agent-scope: bypass XCD L2, hit MALL) access ----
__device__ __forceinline__ float ldsc(const float* p) {
  return __hip_atomic_load(const_cast<float*>(p), __ATOMIC_RELAXED, __HIP_MEMORY_SCOPE_AGENT);
}
__device__ __forceinline__ void stsc(float* p, float v) {
  __hip_atomic_store(p, v, __ATOMIC_RELAXED, __HIP_MEMORY_SCOPE_AGENT);
}
__device__ __forceinline__ int ldsci(const int* p) {
  return __hip_atomic_load(const_cast<int*>(p), __ATOMIC_RELAXED, __HIP_MEMORY_SCOPE_AGENT);
}
__device__ __forceinline__ void stsci(int* p, int v) {
  __hip_atomic_store(p, v, __ATOMIC_RELAXED, __HIP_MEMORY_SCOPE_AGENT);
}

// global -> LDS async DMA, 4 B/lane, wave-uniform LDS base + lane*4
__device__ __forceinline__ void gload_lds(const float* g, float* l) {
  __builtin_amdgcn_global_load_lds(
      (const __attribute__((address_space(1))) unsigned int*)g,
      (__attribute__((address_space(3))) unsigned int*)l, 4, 0, 0);
}

// ======================= setup kernels (run once) ==========================

__global__ void k_zero(float* __restrict__ p, int n) {
  int i = blockIdx.x * blockDim.x + threadIdx.x;
  if (i < n) p[i] = 0.0f;
}

__global__ void k_wz(const float* __restrict__ z_seq, const float* __restrict__ zw,
                     float* __restrict__ out) {
  int i = blockIdx.x * blockDim.x + threadIdx.x;
  if (i < NB * KPH * LATENT) out[i] = zw[i >> 7] * z_seq[i];
}

__global__ void k_copy(const float* __restrict__ src, float* __restrict__ dst, int n) {
  int i = blockIdx.x * blockDim.x + threadIdx.x;
  if (i < n) dst[i] = src[i];
}

__global__ __launch_bounds__(256) void k_gemm(
    const float* __restrict__ A, int lda,
    const float* __restrict__ W, int ldw, int K,
    float* __restrict__ out, int ostride)
{
  __shared__ float As[32][36];
  __shared__ float Ws[32][64];
  const int t = threadIdx.x;
  const int c0 = blockIdx.x * 64, b0 = blockIdx.y * 32;
  const int c = t & 63, g = t >> 6;
  float acc[8] = {0,0,0,0,0,0,0,0};
  const int ra = t >> 3, ka = (t & 7) << 2;
  for (int k0 = 0; k0 < K; k0 += 32) {
    const float4 a4 = *reinterpret_cast<const float4*>(A + (size_t)(b0 + ra) * lda + k0 + ka);
    As[ra][ka] = a4.x; As[ra][ka+1] = a4.y; As[ra][ka+2] = a4.z; As[ra][ka+3] = a4.w;
    #pragma unroll
    for (int e = 0; e < 8; e++) {
      int li = t + e * 256;
      Ws[li >> 6][li & 63] = W[(size_t)(k0 + (li >> 6)) * ldw + c0 + (li & 63)];
    }
    __syncthreads();
    #pragma unroll
    for (int kk = 0; kk < 32; kk++) {
      float wv = Ws[kk][c];
      #pragma unroll
      for (int i = 0; i < 8; i++) acc[i] += As[g*8+i][kk] * wv;
    }
    __syncthreads();
  }
  #pragma unroll
  for (int i = 0; i < 8; i++)
    out[(size_t)(b0 + g * 8 + i) * ostride + c0 + c] = acc[i];
}

__global__ void k_init(const float* __restrict__ zw,
                       int* __restrict__ cur, int* __restrict__ tip, int* __restrict__ pos,
                       int* __restrict__ done, float* __restrict__ gf, int* __restrict__ iph,
                       int* __restrict__ nxt0, int* __restrict__ act)
{
  int b = blockIdx.x * blockDim.x + threadIdx.x;
  if (b < NB) {
    int a0 = zw[b*3+0] > 0.01f;
    act[b*3+0] = a0;
    act[b*3+1] = zw[b*3+1] > 0.01f;
    act[b*3+2] = zw[b*3+2] > 0.01f;
    cur[b] = 0; tip[b] = 0; pos[b] = 0; done[b] = !a0;   // version 0
    gf[b] = a0 ? 1.0f : 0.0f; iph[b] = 0;
    nxt0[b] = 1;                                          // BOS
  }
}

// ======================= persistent decode =================================

struct DecP {
  const float *temb, *Wq, *Wk, *Wv, *Wo, *Wco, *W1, *W2, *Wout;
  const float *MCK, *MCV, *WCAT;
  float *KC, *VC, *XS, *X2, *X3, *X, *Qb, *CQ, *H1, *PV, *GF;
  int *PI, *CUR, *TIP, *POS, *DONE, *IPH, *NXT0, *ACT;
  float *TOK, *GEN, *BND, *HID;
  unsigned *bar;
};

// hierarchical barrier: 64 arrival counters (8 blocks each); block 0 wave 0
// detects (1 counter per lane), then 8 replicated go lines; others poll one.
__device__ __forceinline__ void gsync(unsigned* bar, unsigned epoch) {
  const int t = threadIdx.x, blk = blockIdx.x;
  __syncthreads();
  if (t == 0)
    __hip_atomic_fetch_add(&bar[(blk & 63) * 32], 1u,
                           __ATOMIC_RELAXED, __HIP_MEMORY_SCOPE_AGENT);
  if (blk == 0) {
    if (t < 64) {
      const unsigned tg = epoch * (NBLK / 64);
      while (__hip_atomic_load(&bar[t * 32], __ATOMIC_RELAXED, __HIP_MEMORY_SCOPE_AGENT) < tg)
        __builtin_amdgcn_s_sleep(2);
      if (t < 8)
        __hip_atomic_store(&bar[2048 + t * 32], epoch,
                           __ATOMIC_RELAXED, __HIP_MEMORY_SCOPE_AGENT);
    }
  } else if (t == 0) {
    while (__hip_atomic_load(&bar[2048 + (blk & 7) * 32],
                             __ATOMIC_RELAXED, __HIP_MEMORY_SCOPE_AGENT) < epoch)
      __builtin_amdgcn_s_sleep(8);
  }
  __syncthreads();
}

__global__ __launch_bounds__(256, 2) void k_decode(DecP p) {
  __shared__ float Ws2[2][64][64];     // 32 KB: W slab DMA double-buffer
  __shared__ float U[8704];            // 34 KB phase-union scratch
  __shared__ int   snxt[8];

  const int t = threadIdx.x;
  const int blk = blockIdx.x;
  unsigned ep = 0;

  // 64col x 8row fp32 GEMM, slab K=64, W via global_load_lds double-buffer.
  auto gemm8 = [&](int bx, int by, const float* A, int lda,
                   const float* W, int ldw, int K,
                   const float* R, int rs,
                   float* out, int os, int oo, int dogelu) {
    float (*As2)[8][72] = (float(*)[8][72])U;
    const int c0 = bx * 64, b0 = by * 8;
    const int c = t & 63, g = t >> 6;
    const int ar = t & 7, ak = t >> 3;
    const int nslab = K >> 6;
    float acc0 = 0.f, acc1 = 0.f;
    float res0 = 0.f, res1 = 0.f;
    if (R) {
      res0 = ldsc(R + (size_t)(b0 + g * 2 + 0) * rs + c0 + c);
      res1 = ldsc(R + (size_t)(b0 + g * 2 + 1) * rs + c0 + c);
    }
    float aR0 = ldsc(A + (size_t)(b0 + ar) * lda + ak);
    float aR1 = ldsc(A + (size_t)(b0 + ar) * lda + 32 + ak);
    #pragma unroll
    for (int e = 0; e < 16; e++)
      gload_lds(W + (size_t)(g * 16 + e) * ldw + c0 + c, &Ws2[0][g * 16 + e][0]);
    for (int j = 0; j < nslab; j++) {
      const int cur = j & 1;
      As2[cur][ar][ak] = aR0;
      As2[cur][ar][ak + 32] = aR1;
      __syncthreads();
      if (j + 1 < nslab) {
        aR0 = ldsc(A + (size_t)(b0 + ar) * lda + (j + 1) * 64 + ak);
        aR1 = ldsc(A + (size_t)(b0 + ar) * lda + (j + 1) * 64 + 32 + ak);
        #pragma unroll
        for (int e = 0; e < 16; e++)
          gload_lds(W + (size_t)((j + 1) * 64 + g * 16 + e) * ldw + c0 + c,
                    &Ws2[cur ^ 1][g * 16 + e][0]);
      }
      #pragma unroll
      for (int kk = 0; kk < 64; kk++) {
        float wv = Ws2[cur][kk][c];
        acc0 += As2[cur][g * 2 + 0][kk] * wv;
        acc1 += As2[cur][g * 2 + 1][kk] * wv;
      }
      __syncthreads();
    }
    #pragma unroll
    for (int i = 0; i < 2; i++) {
      float v = (i == 0) ? acc0 : acc1;
      int b = b0 + g * 2 + i;
      v += (i == 0) ? res0 : res1;
      if (dogelu) {
        float x3 = v * v * v;
        v = 0.5f * v * (1.0f + tanhf(0.7978845608028654f * (v + 0.044715f * x3)));
      }
      stsc(out + (size_t)b * os + oo + c0 + c, v);
    }
  };

  // gemm8 with A rows gathered from temb via snxt (for QKV)
  auto gemm8g = [&](int bx, int b0, const float* W,
                    float* out, int os, int oo) {
    float (*As2)[8][72] = (float(*)[8][72])U;
    const int c0 = bx * 64;
    const int c = t & 63, g = t >> 6;
    const int ar = t & 7, ak = t >> 3;
    float acc0 = 0.f, acc1 = 0.f;
    const float* Ar = p.temb + (size_t)snxt[ar] * 512;
    float aR0 = Ar[ak];
    float aR1 = Ar[32 + ak];
    #pragma unroll
    for (int e = 0; e < 16; e++)
      gload_lds(W + (size_t)(g * 16 + e) * 512 + c0 + c, &Ws2[0][g * 16 + e][0]);
    for (int j = 0; j < 8; j++) {
      const int cur = j & 1;
      As2[cur][ar][ak] = aR0;
      As2[cur][ar][ak + 32] = aR1;
      __syncthreads();
      if (j + 1 < 8) {
        aR0 = Ar[(j + 1) * 64 + ak];
        aR1 = Ar[(j + 1) * 64 + 32 + ak];
        #pragma unroll
        for (int e = 0; e < 16; e++)
          gload_lds(W + (size_t)((j + 1) * 64 + g * 16 + e) * 512 + c0 + c,
                    &Ws2[cur ^ 1][g * 16 + e][0]);
      }
      #pragma unroll
      for (int kk = 0; kk < 64; kk++) {
        float wv = Ws2[cur][kk][c];
        acc0 += As2[cur][g * 2 + 0][kk] * wv;
        acc1 += As2[cur][g * 2 + 1][kk] * wv;
      }
      __syncthreads();
    }
    #pragma unroll
    for (int i = 0; i < 2; i++) {
      float v = (i == 0) ? acc0 : acc1;
      int b = b0 + g * 2 + i;
      stsc(out + (size_t)b * os + oo + c0 + c, v);
    }
  };

  // logits tile 64col x 32row, K=512, async-W pipeline + argmax partial
  auto logits_tile = [&](int bx, int by) {
    float (*AsL)[32][72] = (float(*)[32][72])U;
    float (*rv)[65] = (float(*)[65])(U + 4608);
    const int c0 = bx * 64, b0 = by * 32;
    const int c = t & 63, g = t >> 6;
    const int ar = t & 31, akb = (t >> 5) * 8;
    float acc[8] = {0,0,0,0,0,0,0,0};
    float aR[8];
    const float* Ab = p.X + (size_t)(b0 + ar) * 512 + akb;
    #pragma unroll
    for (int u = 0; u < 8; u++) aR[u] = ldsc(Ab + u);
    #pragma unroll
    for (int e = 0; e < 16; e++)
      gload_lds(p.Wout + (size_t)(g * 16 + e) * VOC + c0 + c, &Ws2[0][g * 16 + e][0]);
    for (int j = 0; j < 8; j++) {
      const int cur = j & 1;
      #pragma unroll
      for (int u = 0; u < 8; u++) AsL[cur][ar][akb + u] = aR[u];
      __syncthreads();
      if (j + 1 < 8) {
        #pragma unroll
        for (int u = 0; u < 8; u++) aR[u] = ldsc(Ab + (j + 1) * 64 + u);
        #pragma unroll
        for (int e = 0; e < 16; e++)
          gload_lds(p.Wout + (size_t)((j + 1) * 64 + g * 16 + e) * VOC + c0 + c,
                    &Ws2[cur ^ 1][g * 16 + e][0]);
      }
      #pragma unroll
      for (int kk = 0; kk < 64; kk++) {
        float wv = Ws2[cur][kk][c];
        #pragma unroll
        for (int i = 0; i < 8; i++) acc[i] += AsL[cur][g * 8 + i][kk] * wv;
      }
      __syncthreads();
    }
    #pragma unroll
    for (int i = 0; i < 8; i++) rv[g*8+i][c] = acc[i];
    __syncthreads();
    if (t < 32) {
      float best = rv[t][0]; int bi = 0;
      for (int cc = 1; cc < 64; cc++) {        // serial -> first-index tie-break
        float v = rv[t][cc];
        if (v > best) { best = v; bi = cc; }
      }
      stsc(&p.PV[(size_t)(b0 + t) * 125 + bx], best);
      stsci(&p.PI[(size_t)(b0 + t) * 125 + bx], c0 + bi);
    }
    __syncthreads();
  };

  // argmax-finish + state machine for rows b0..b0+7 (redundant across blocks;
  // identical values -> benign). desig block also writes outputs.
  auto state_phase = [&](int s, int b0, int desig) {
    const int r = t >> 5, j = t & 31, b = b0 + r;
    const int vOld = (s - 1) & 1, vNew = s & 1;
    if (s > 0) {
      float bv = -INFINITY; int bix = 0x7fffffff;
      for (int i = j; i < 125; i += 32) {
        float v = ldsc(&p.PV[(size_t)b * 125 + i]);
        int  id = ldsci(&p.PI[(size_t)b * 125 + i]);
        if (v > bv || (v == bv && id < bix)) { bv = v; bix = id; }
      }
      #pragma unroll
      for (int off = 16; off; off >>= 1) {
        float v2 = __shfl_xor(bv, off, 64);
        int   i2 = __shfl_xor(bix, off, 64);
        if (v2 > bv || (v2 == bv && i2 < bix)) { bv = v2; bix = i2; }
      }
      if (j == 0) {
        int nxt = bix;
        int dn = ldsci(&p.DONE[vOld*NB+b]); int live = !dn;
        int pp = ldsci(&p.POS[vOld*NB+b]);
        int tp = ldsci(&p.TIP[vOld*NB+b]);
        int cp = ldsci(&p.CUR[vOld*NB+b]);
        if (desig && pp < MAXTOK) {
          p.TOK[(size_t)b*MAXTOK+pp] = live ? (float)nxt : 0.0f;
          p.GEN[(size_t)b*MAXTOK+pp] = live ? 1.0f : 0.0f;
        }
        pp += live; tp += live;
        int eos = (nxt == 2) && (tp >= 1);
        int sw = (eos || (tp >= MAXPER)) && live;
        cp += sw;
        if (sw) tp = 0;
        int cpc = cp < 2 ? cp : 2;
        if (desig && sw && (cp < KPH)) p.BND[(size_t)b*KPH+cpc] = (float)pp;
        dn = dn || (cp >= KPH) || (sw && !p.ACT[b*3+cpc]);
        stsci(&p.CUR[vNew*NB+b], cp);
        stsci(&p.TIP[vNew*NB+b], tp);
        stsci(&p.POS[vNew*NB+b], pp);
        stsci(&p.DONE[vNew*NB+b], dn);
        stsc(&p.GF[vNew*NB+b], (p.ACT[b*3+cpc] && !dn) ? 1.0f : 0.0f);
        stsci(&p.IPH[vNew*NB+b], cpc);
        snxt[r] = nxt;
      }
    } else {
      if (j == 0) snxt[r] = p.NXT0[b];
    }
    __syncthreads();
  };

  for (int s = 0; s < MAXTOK; s++) {
    // ---- A': state (t=s-1) + Q,K,V projections (slot s) ----
    if (blk < 384) {
      int which = blk >> 7;                       // 0=Q 1=K 2=V
      int loc = blk & 127, bx = loc & 7, by = loc >> 3;
      int b0 = by * 8;
      int desig = (which == 0 && bx == 0);
      state_phase(s, b0, desig);
      if (desig) {                                // XS-XIN + HID[s-1]
        #pragma unroll
        for (int rep = 0; rep < 16; rep++) {
          int idx = t + rep * 256;
          int rr = idx >> 9, cc = idx & 511;
          stsc(&p.XS[(size_t)(b0 + rr) * 1024 + cc],
               p.temb[(size_t)snxt[rr] * 512 + cc]);
          if (s > 0)
            p.HID[((size_t)(s - 1) * NB + (b0 + rr)) * 512 + cc] =
                ldsc(&p.X[(size_t)(b0 + rr) * 512 + cc]);
        }
      }
      if (which == 0)      gemm8g(bx, b0, p.Wq, p.Qb, 512, 0);
      else if (which == 1) gemm8g(bx, b0, p.Wk, p.KC, CT*512, s*512);
      else                 gemm8g(bx, b0, p.Wv, p.VC, CT*512, s*512);
    }
    gsync(p.bar, ++ep);

    // ---- B: self-attention, T = s+1, one wave per (b,h) ----
    if (blk < 256) {
      float (*aux)[224] = (float(*)[224])U;
      const int T = s + 1;
      int lane = t & 63, w = t >> 6;
      int task = blk * 4 + w, b = task >> 3, h = task & 7;
      float* ql = aux[w];
      float* sc = aux[w] + 64;
      ql[lane] = ldsc(&p.Qb[(size_t)b * 512 + h * 64 + lane]);
      __syncthreads();
      float lmax = -INFINITY;
      for (int s0 = lane; s0 < T; s0 += 64) {
        const float4* kp = reinterpret_cast<const float4*>(p.KC + ((size_t)b * CT + s0) * 512 + h * 64);
        float d = 0.0f;
        #pragma unroll
        for (int e = 0; e < 16; e++) {
          float4 k4 = kp[e];
          d += ql[4*e]*k4.x + ql[4*e+1]*k4.y + ql[4*e+2]*k4.z + ql[4*e+3]*k4.w;
        }
        d *= SCALE;
        sc[s0] = d;
        lmax = fmaxf(lmax, d);
      }
      #pragma unroll
      for (int off = 32; off; off >>= 1) lmax = fmaxf(lmax, __shfl_xor(lmax, off, 64));
      float lsum = 0.0f;
      for (int s0 = lane; s0 < T; s0 += 64) {
        float e = expf(sc[s0] - lmax);
        sc[s0] = e; lsum += e;
      }
      #pragma unroll
      for (int off = 32; off; off >>= 1) lsum += __shfl_xor(lsum, off, 64);
      __syncthreads();
      float inv = 1.0f / lsum;
      float acc = 0.0f;
      const float* vb = p.VC + (size_t)b * CT * 512 + h * 64 + lane;
      for (int s0 = 0; s0 < T; s0++) acc += sc[s0] * vb[(size_t)s0 * 512];
      stsc(&p.XS[(size_t)b * 1024 + 512 + h * 64 + lane], acc * inv);
    }
    gsync(p.bar, ++ep);

    // ---- C: X2 = XIN + SA@Wo ; CQ = [XIN|SA]@WCAT (K=1024 fused) ----
    if (blk < 128)
      gemm8(blk & 7, blk >> 3, p.XS + 512, 1024, p.Wo, 512, 512, p.XS, 1024, p.X2, 512, 0, 0);
    else if (blk < 256)
      gemm8((blk-128) & 7, (blk-128) >> 3, p.XS, 1024, p.WCAT, 512, 1024, nullptr, 0, p.CQ, 512, 0, 0);
    gsync(p.bar, ++ep);

    // ---- E': fused cross-attention + X3 = X2 + CA@Wco, one block per b ----
    if (blk < NB) {
      const int b = blk;
      const int vNew = s & 1;
      float* cq  = U;            // 512
      float* ca  = U + 512;      // 512
      float* scs = U + 1024;     // 64
      cq[t]       = ldsc(&p.CQ[(size_t)b * 512 + t]);
      cq[t + 256] = ldsc(&p.CQ[(size_t)b * 512 + t + 256]);
      __syncthreads();
      float gate = ldsc(&p.GF[vNew*NB+b]);
      int ip = ldsci(&p.IPH[vNew*NB+b]);
      const float* mk = p.MCK + (size_t)(b * KPH + ip) * NMEM * 512;
      if (t < 64) {
        int h = t >> 3, m = t & 7;
        const float4* kp = reinterpret_cast<const float4*>(mk + m * 512 + h * 64);
        float d = 0.0f;
        #pragma unroll
        for (int e = 0; e < 16; e++) {
          float4 k4 = kp[e];
          d += cq[h*64+4*e]*k4.x + cq[h*64+4*e+1]*k4.y + cq[h*64+4*e+2]*k4.z + cq[h*64+4*e+3]*k4.w;
        }
        scs[t] = d * SCALE * gate;
      }
      __syncthreads();
      const float* mv = p.MCV + (size_t)(b * KPH + ip) * NMEM * 512;
      #pragma unroll
      for (int half = 0; half < 2; half++) {
        int c = t + half * 256;
        int h = c >> 6;
        float mx = scs[h*8];
        #pragma unroll
        for (int m = 1; m < 8; m++) mx = fmaxf(mx, scs[h*8+m]);
        float ee[8]; float sum = 0.0f;
        #pragma unroll
        for (int m = 0; m < 8; m++) { ee[m] = expf(scs[h*8+m] - mx); sum += ee[m]; }
        float a = 0.0f;
        #pragma unroll
        for (int m = 0; m < 8; m++) a += ee[m] * mv[(size_t)m * 512 + c];
        ca[c] = gate * a / sum;
      }
      __syncthreads();
      // X3[b][c] = X2[b][c] + sum_k ca[k]*Wco[k][c]   (serial k, R7 order)
      #pragma unroll
      for (int half = 0; half < 2; half++) {
        int c = t + half * 256;
        float acc = 0.0f;
        const float* wc = p.Wco + c;
        for (int k = 0; k < 512; k++) acc += ca[k] * wc[(size_t)k * 512];
        stsc(&p.X3[(size_t)b * 512 + c], acc + ldsc(&p.X2[(size_t)b * 512 + c]));
      }
    }
    gsync(p.bar, ++ep);

    // ---- F: H1 = gelu(X3@W1), N=2048, all 512 blocks ----
    gemm8(blk & 31, blk >> 5, p.X3, 512, p.W1, 2048, 512, nullptr, 0, p.H1, 2048, 0, 1);
    gsync(p.bar, ++ep);

    // ---- G: X = X3 + H1@W2, K=2048 ----
    if (blk < 128)
      gemm8(blk & 7, blk >> 3, p.H1, 2048, p.W2, 512, 2048, p.X3, 512, p.X, 512, 0, 0);
    gsync(p.bar, ++ep);

    // ---- H: logits + argmax partials; col tiles XCD-pinned (bx%8==blk%8) ----
    {
      const int x = blk & 7, idx2 = blk >> 3;
      const int ii = idx2 & 15, by = idx2 >> 4;
      const int bx = x + 8 * ii;
      if (bx < 125) logits_tile(bx, by);
    }
    gsync(p.bar, ++ep);
  }

  // ---- epilogue: state machine t=143 + TOK/GEN/BND + HID[143] ----
  if (blk < 128 && (blk & 7) == 0) {
    const int b0 = (blk >> 3) * 8;
    state_phase(MAXTOK, b0, 1);
    #pragma unroll
    for (int rep = 0; rep < 8; rep++) {
      int idx = t + rep * 256;
      int rr = idx >> 9, cc = idx & 511;
      p.HID[((size_t)(MAXTOK - 1) * NB + (b0 + rr)) * 512 + cc] =
          ldsc(&p.X[(size_t)(b0 + rr) * 512 + cc]);
    }
  }
}

// ======================= host ==============================================

extern "C" void kernel_launch(void* const* d_in, const int* in_sizes, int n_in,
                              void* d_out, int out_size, void* d_ws, size_t ws_size,
                              hipStream_t stream)
{
  const float* z_seq = (const float*)d_in[0];
  const float* z_w   = (const float*)d_in[1];
  const float* W_l2d = (const float*)d_in[2];
  const float* temb  = (const float*)d_in[3];
  const float* Wq  = (const float*)d_in[4];
  const float* Wk  = (const float*)d_in[5];
  const float* Wv  = (const float*)d_in[6];
  const float* Wo  = (const float*)d_in[7];
  const float* Wcq = (const float*)d_in[8];
  const float* Wck = (const float*)d_in[9];
  const float* Wcv = (const float*)d_in[10];
  const float* Wco = (const float*)d_in[11];
  const float* W1  = (const float*)d_in[12];
  const float* W2  = (const float*)d_in[13];
  const float* Wout= (const float*)d_in[14];

  float* fw = (float*)d_ws;
  size_t o = 4096;   // first 4096 words: barrier counters + go lines
  auto alloc = [&](size_t n) { float* r = fw + o; o += (n + 63) & ~(size_t)63; return r; };
  float* MCK = alloc((size_t)NB*KPH*NMEM*HD);
  float* MCV = alloc((size_t)NB*KPH*NMEM*HD);
  float* MEM = alloc((size_t)NB*KPH*NMEM*HD);   // reused as WCAT after setup
  float* KC  = alloc((size_t)NB*CT*HD);
  float* VC  = alloc((size_t)NB*CT*HD);
  float* XS  = alloc((size_t)NB*1024);          // [XIN | SA]
  float* X2  = alloc((size_t)NB*HD);
  float* X3  = alloc((size_t)NB*HD);
  float* X   = alloc((size_t)NB*HD);
  float* Qb  = alloc((size_t)NB*HD);
  float* CQ  = alloc((size_t)NB*HD);
  float* H1  = alloc((size_t)NB*4*HD);
  float* WZ  = alloc((size_t)NB*KPH*LATENT);
  float* PV  = alloc((size_t)NB*125);
  float* GF  = alloc(2*NB);
  int* ib = (int*)alloc(0);
  size_t io = 0;
  auto ialloc = [&](size_t n) { int* r = ib + io; io += (n + 63) & ~(size_t)63; return r; };
  int* PI   = ialloc((size_t)NB*125);
  int* CUR  = ialloc(2*NB);
  int* TIP  = ialloc(2*NB);
  int* POS  = ialloc(2*NB);
  int* DONE = ialloc(2*NB);
  int* IPH  = ialloc(2*NB);
  int* NXT0 = ialloc(NB);
  int* ACT  = ialloc(NB*KPH);

  float* WCAT = MEM;   // [Wcq ; Wo@Wcq]  (1024 x 512) — overlays MEM after setup

  float* out_f = (float*)d_out;
  float* TOK  = out_f;
  float* GEN  = out_f + NB*MAXTOK;
  float* BND  = out_f + 2*NB*MAXTOK;
  float* HID  = out_f + 2*NB*MAXTOK + NB*KPH;

  // ---- one-time setup (plain kernels; dispatch boundaries give coherence) ----
  k_zero<<<16, 256, 0, stream>>>(fw, 4096);                               // barrier
  int nz = 2*NB*MAXTOK + NB*KPH;
  k_zero<<<(nz + 255)/256, 256, 0, stream>>>(out_f, nz);                  // tok/gen/bnd
  k_wz<<<(NB*KPH*LATENT + 255)/256, 256, 0, stream>>>(z_seq, z_w, WZ);
  k_gemm<<<dim3(64,12),256,0,stream>>>(WZ, 128, W_l2d, 4096, 128, MEM, 4096);
  k_gemm<<<dim3(8,96),256,0,stream>>>(MEM, 512, Wck, 512, 512, MCK, 512);
  k_gemm<<<dim3(8,96),256,0,stream>>>(MEM, 512, Wcv, 512, 512, MCV, 512);
  k_gemm<<<dim3(8,16),256,0,stream>>>(Wo, 512, Wcq, 512, 512, WCAT + (size_t)512*512, 512);
  k_copy<<<(512*512 + 255)/256, 256, 0, stream>>>(Wcq, WCAT, 512*512);
  k_init<<<1,128,0,stream>>>(z_w, CUR, TIP, POS, DONE, GF, IPH, NXT0, ACT);

  // ---- persistent decode: plain launch; 512 blocks, 2/CU co-resident ----
  DecP prm;
  prm.temb = temb; prm.Wq = Wq; prm.Wk = Wk; prm.Wv = Wv; prm.Wo = Wo;
  prm.Wco = Wco; prm.W1 = W1; prm.W2 = W2; prm.Wout = Wout;
  prm.MCK = MCK; prm.MCV = MCV; prm.WCAT = WCAT;
  prm.KC = KC; prm.VC = VC; prm.XS = XS; prm.X2 = X2; prm.X3 = X3; prm.X = X;
  prm.Qb = Qb; prm.CQ = CQ; prm.H1 = H1; prm.PV = PV; prm.GF = GF;
  prm.PI = PI; prm.CUR = CUR; prm.TIP = TIP; prm.POS = POS; prm.DONE = DONE;
  prm.IPH = IPH; prm.NXT0 = NXT0; prm.ACT = ACT;
  prm.TOK = TOK; prm.GEN = GEN; prm.BND = BND; prm.HID = HID;
  prm.bar = (unsigned*)d_ws;

  k_decode<<<dim3(NBLK), dim3(256), 0, stream>>>(prm);
}